// Round 1
// baseline (1106.364 us; speedup 1.0000x reference)
//
#include <hip/hip_runtime.h>
#include <hip/hip_bf16.h>
#include <math.h>

// Problem constants (match reference)
#define NN   20000
#define EE   320000
#define OBS  256
#define HID  256
#define EMB  128
#define MLPH 512
#define ACT  64

// ---------------- degree kernels ----------------
__global__ void init_deg(float* __restrict__ dout, float* __restrict__ din, int n) {
    int i = blockIdx.x * blockDim.x + threadIdx.x;
    if (i < n) { dout[i] = 1.0f; din[i] = 1.0f; }  // self-loop contributes 1 to both
}

__global__ void edge_deg(const int* __restrict__ src, const int* __restrict__ dst,
                         float* __restrict__ dout, float* __restrict__ din, int e) {
    for (int i = blockIdx.x * blockDim.x + threadIdx.x; i < e; i += gridDim.x * blockDim.x) {
        atomicAdd(&dout[src[i]], 1.0f);
        atomicAdd(&din[dst[i]], 1.0f);
    }
}

__global__ void deg_to_dinv(float* __restrict__ dout, float* __restrict__ din, int n) {
    int i = blockIdx.x * blockDim.x + threadIdx.x;
    if (i < n) {
        dout[i] = rsqrtf(fmaxf(dout[i], 1.0f));
        din[i]  = rsqrtf(fmaxf(din[i], 1.0f));
    }
}

// ---------------- fp32 tiled GEMM ----------------
// C[M x Nout] = act( rs[i] * (X[M x K] @ W[K x Nout]) + bias[j] )
// BM=BN=64, BK=16, 256 threads, 4x4 per thread.
#define BM 64
#define BN 64
#define BK 16

__global__ __launch_bounds__(256) void gemm_f32(
    const float* __restrict__ X, const float* __restrict__ W, float* __restrict__ C,
    int M, int K, int Nout,
    const float* __restrict__ rs, const float* __restrict__ bias, int act)
{
    __shared__ float As[BK][BM];
    __shared__ float Bs[BK][BN];

    const int row0 = blockIdx.x * BM;
    const int col0 = blockIdx.y * BN;
    const int tid  = threadIdx.x;
    const int tx   = tid & 15;
    const int ty   = tid >> 4;

    float acc[4][4] = {};

    // A-tile load mapping: each thread loads float4 of one row
    const int ar   = tid & 63;
    const int ac4  = (tid >> 6) * 4;
    const int arow = row0 + ar;
    const bool arow_ok = (arow < M);

    // B(W)-tile load mapping
    const int bk  = tid >> 4;          // 0..15
    const int bn4 = (tid & 15) * 4;    // 0..60

    for (int k0 = 0; k0 < K; k0 += BK) {
        float4 a4 = make_float4(0.f, 0.f, 0.f, 0.f);
        if (arow_ok)
            a4 = *reinterpret_cast<const float4*>(&X[(size_t)arow * K + k0 + ac4]);
        As[ac4 + 0][ar] = a4.x;
        As[ac4 + 1][ar] = a4.y;
        As[ac4 + 2][ar] = a4.z;
        As[ac4 + 3][ar] = a4.w;

        float4 b4 = *reinterpret_cast<const float4*>(&W[(size_t)(k0 + bk) * Nout + col0 + bn4]);
        *reinterpret_cast<float4*>(&Bs[bk][bn4]) = b4;

        __syncthreads();
#pragma unroll
        for (int k = 0; k < BK; ++k) {
            float4 av = *reinterpret_cast<const float4*>(&As[k][ty * 4]);
            float4 bv = *reinterpret_cast<const float4*>(&Bs[k][tx * 4]);
            float a_[4] = {av.x, av.y, av.z, av.w};
            float b_[4] = {bv.x, bv.y, bv.z, bv.w};
#pragma unroll
            for (int i = 0; i < 4; ++i)
#pragma unroll
                for (int j = 0; j < 4; ++j)
                    acc[i][j] = fmaf(a_[i], b_[j], acc[i][j]);
        }
        __syncthreads();
    }

#pragma unroll
    for (int i = 0; i < 4; ++i) {
        int r = row0 + ty * 4 + i;
        if (r >= M) continue;
        float rsv = rs ? rs[r] : 1.0f;
#pragma unroll
        for (int j = 0; j < 4; ++j) {
            int c = col0 + tx * 4 + j;
            float v = acc[i][j] * rsv;
            if (bias) v += bias[c];
            if (act == 1) v = fmaxf(v, 0.0f);
            C[(size_t)r * Nout + c] = v;
        }
    }
}

// ---------------- edge scatter-add ----------------
// B[dst[e]][:] += A[src[e]][:]  (B pre-initialized with self-loop term = A)
template <int F>
__global__ void scatter_add(const float* __restrict__ A, float* __restrict__ B,
                            const int* __restrict__ src, const int* __restrict__ dst, int e)
{
    const int lane_f = threadIdx.x & (F - 1);
    const int eo     = threadIdx.x / F;
    const int epb    = blockDim.x / F;
    for (int i = blockIdx.x * epb + eo; i < e; i += gridDim.x * epb) {
        int s = src[i];
        int d = dst[i];
        float v = A[(size_t)s * F + lane_f];
        atomicAdd(&B[(size_t)d * F + lane_f], v);
    }
}

// ---------------- post-scatter epilogue ----------------
// y = act( y * dinv_in[i] + bias[j] ); act: 1 = relu, 2 = sigmoid + 1e-8
__global__ void post_scatter(float* __restrict__ Y, const float* __restrict__ dinv_in,
                             const float* __restrict__ bias, int n_rows, int F, int act)
{
    int idx = blockIdx.x * blockDim.x + threadIdx.x;
    int total = n_rows * F;
    if (idx >= total) return;
    int i = idx / F;
    int j = idx - i * F;
    float v = Y[idx] * dinv_in[i] + bias[j];
    if (act == 1) v = fmaxf(v, 0.0f);
    else          v = 1.0f / (1.0f + expf(-v)) + 1e-8f;
    Y[idx] = v;
}

// ---------------- softmax over 64 logits, one wave per row ----------------
__global__ __launch_bounds__(256) void softmax64(const float* __restrict__ logits,
                                                 float* __restrict__ out, int n_rows)
{
    int wave = threadIdx.x >> 6;
    int lane = threadIdx.x & 63;
    int row  = blockIdx.x * 4 + wave;
    if (row >= n_rows) return;
    float v = logits[(size_t)row * 64 + lane];
    float m = v;
#pragma unroll
    for (int o = 32; o > 0; o >>= 1) m = fmaxf(m, __shfl_xor(m, o));
    float e = expf(v - m);
    float s = e;
#pragma unroll
    for (int o = 32; o > 0; o >>= 1) s += __shfl_xor(s, o);
    out[(size_t)row * 64 + lane] = e / s;
}

// ---------------- launcher ----------------
extern "C" void kernel_launch(void* const* d_in, const int* in_sizes, int n_in,
                              void* d_out, int out_size, void* d_ws, size_t ws_size,
                              hipStream_t stream)
{
    const float* x   = (const float*)d_in[0];
    const int*   src = (const int*)d_in[1];
    const int*   dst = (const int*)d_in[2];
    const float* Wg1 = (const float*)d_in[3];
    const float* bg1 = (const float*)d_in[4];
    const float* Wg2 = (const float*)d_in[5];
    const float* bg2 = (const float*)d_in[6];
    const float* Wg3 = (const float*)d_in[7];
    const float* bg3 = (const float*)d_in[8];
    const float* W1  = (const float*)d_in[9];
    const float* b1  = (const float*)d_in[10];
    const float* W2  = (const float*)d_in[11];
    const float* b2  = (const float*)d_in[12];
    const float* W3  = (const float*)d_in[13];
    const float* b3  = (const float*)d_in[14];

    float* out  = (float*)d_out;
    float* prob = out;                 // [N x 64]
    float* gnn  = out + (size_t)NN * ACT;  // [N x 128]

    float* ws       = (float*)d_ws;
    float* dinv_out = ws;
    float* dinv_in  = ws + NN;
    float* A        = ws + 2 * NN;                  // N x 512 scratch
    float* B        = A + (size_t)NN * 512;         // N x 512 scratch

    // --- degrees -> dinv ---
    init_deg<<<(NN + 255) / 256, 256, 0, stream>>>(dinv_out, dinv_in, NN);
    edge_deg<<<1024, 256, 0, stream>>>(src, dst, dinv_out, dinv_in, EE);
    deg_to_dinv<<<(NN + 255) / 256, 256, 0, stream>>>(dinv_out, dinv_in, NN);

    const int rb = (NN + BM - 1) / BM;   // 313 row tiles

    // --- GCN layer 1: A = dinv_out * (x @ Wg1) ---
    gemm_f32<<<dim3(rb, HID / BN), 256, 0, stream>>>(x, Wg1, A, NN, OBS, HID, dinv_out, nullptr, 0);
    hipMemcpyAsync(B, A, (size_t)NN * HID * sizeof(float), hipMemcpyDeviceToDevice, stream);
    scatter_add<HID><<<2048, 256, 0, stream>>>(A, B, src, dst, EE);
    post_scatter<<<(NN * HID + 255) / 256, 256, 0, stream>>>(B, dinv_in, bg1, NN, HID, 1);

    // --- GCN layer 2 ---
    gemm_f32<<<dim3(rb, HID / BN), 256, 0, stream>>>(B, Wg2, A, NN, HID, HID, dinv_out, nullptr, 0);
    hipMemcpyAsync(B, A, (size_t)NN * HID * sizeof(float), hipMemcpyDeviceToDevice, stream);
    scatter_add<HID><<<2048, 256, 0, stream>>>(A, B, src, dst, EE);
    post_scatter<<<(NN * HID + 255) / 256, 256, 0, stream>>>(B, dinv_in, bg2, NN, HID, 1);

    // --- GCN layer 3 -> gnn_output (in d_out) ---
    gemm_f32<<<dim3(rb, EMB / BN), 256, 0, stream>>>(B, Wg3, A, NN, HID, EMB, dinv_out, nullptr, 0);
    hipMemcpyAsync(gnn, A, (size_t)NN * EMB * sizeof(float), hipMemcpyDeviceToDevice, stream);
    scatter_add<EMB><<<2048, 256, 0, stream>>>(A, gnn, src, dst, EE);
    post_scatter<<<(NN * EMB + 255) / 256, 256, 0, stream>>>(gnn, dinv_in, bg3, NN, EMB, 2);

    // --- MLP ---
    gemm_f32<<<dim3(rb, MLPH / BN), 256, 0, stream>>>(gnn, W1, A, NN, EMB, MLPH, nullptr, b1, 1);
    gemm_f32<<<dim3(rb, MLPH / BN), 256, 0, stream>>>(A, W2, B, NN, MLPH, MLPH, nullptr, b2, 1);
    gemm_f32<<<dim3(rb, ACT / BN), 256, 0, stream>>>(B, W3, A, NN, MLPH, ACT, nullptr, b3, 0);

    // --- softmax ---
    softmax64<<<(NN + 3) / 4, 256, 0, stream>>>(A, prob, NN);
}

// Round 2
// 579.830 us; speedup vs baseline: 1.9081x; 1.9081x over previous
//
#include <hip/hip_runtime.h>
#include <hip/hip_bf16.h>
#include <math.h>

// Problem constants (match reference)
#define NN   20000
#define EE   320000
#define OBS  256
#define HID  256
#define EMB  128
#define MLPH 512
#define ACT  64

// ---------------- degree / CSR-histogram kernels ----------------
__global__ void init_deg_cnt(float* __restrict__ dout, int* __restrict__ cnt, int n) {
    int i = blockIdx.x * blockDim.x + threadIdx.x;
    if (i < n) { dout[i] = 1.0f; cnt[i] = 0; }   // self-loop contributes 1 to out-degree
}

__global__ void edge_deg(const int* __restrict__ src, const int* __restrict__ dst,
                         float* __restrict__ dout, int* __restrict__ cnt, int e) {
    for (int i = blockIdx.x * blockDim.x + threadIdx.x; i < e; i += gridDim.x * blockDim.x) {
        atomicAdd(&dout[src[i]], 1.0f);
        atomicAdd(&cnt[dst[i]], 1);
    }
}

__global__ void deg_to_dinv(float* __restrict__ dout, float* __restrict__ din,
                            const int* __restrict__ cnt, int n) {
    int i = blockIdx.x * blockDim.x + threadIdx.x;
    if (i < n) {
        dout[i] = rsqrtf(fmaxf(dout[i], 1.0f));
        din[i]  = rsqrtf((float)cnt[i] + 1.0f);   // in-degree includes self-loop, always >= 1
    }
}

// ---------------- one-block exclusive scan -> row_start, cursor ----------------
__global__ __launch_bounds__(1024) void scan_csr(const int* __restrict__ cnt,
                                                 int* __restrict__ row_start,
                                                 int* __restrict__ cursor, int n)
{
    __shared__ int part[1024];
    const int t = threadIdx.x;
    const int chunk = (n + 1023) / 1024;
    const int lo = t * chunk;
    const int hi = min(lo + chunk, n);
    int s = 0;
    for (int i = lo; i < hi; ++i) s += cnt[i];
    part[t] = s;
    __syncthreads();
    for (int off = 1; off < 1024; off <<= 1) {
        int v = (t >= off) ? part[t - off] : 0;
        __syncthreads();
        part[t] += v;
        __syncthreads();
    }
    int run = (t == 0) ? 0 : part[t - 1];
    for (int i = lo; i < hi; ++i) {
        row_start[i] = run;
        cursor[i]    = run;
        run += cnt[i];
    }
    if (t == 1023) row_start[n] = part[1023];
}

__global__ void fill_csr(const int* __restrict__ src, const int* __restrict__ dst,
                         int* __restrict__ cursor, int* __restrict__ csr_src, int e)
{
    for (int i = blockIdx.x * blockDim.x + threadIdx.x; i < e; i += gridDim.x * blockDim.x) {
        int p = atomicAdd(&cursor[dst[i]], 1);
        csr_src[p] = src[i];
    }
}

// ---------------- fp32 tiled GEMM ----------------
// C[M x Nout] = act( rs[i] * (X[M x K] @ W[K x Nout]) + bias[j] )
#define BM 64
#define BN 64
#define BK 16

__global__ __launch_bounds__(256) void gemm_f32(
    const float* __restrict__ X, const float* __restrict__ W, float* __restrict__ C,
    int M, int K, int Nout,
    const float* __restrict__ rs, const float* __restrict__ bias, int act)
{
    __shared__ float As[BK][BM];
    __shared__ float Bs[BK][BN];

    const int row0 = blockIdx.x * BM;
    const int col0 = blockIdx.y * BN;
    const int tid  = threadIdx.x;
    const int tx   = tid & 15;
    const int ty   = tid >> 4;

    float acc[4][4] = {};

    const int ar   = tid & 63;
    const int ac4  = (tid >> 6) * 4;
    const int arow = row0 + ar;
    const bool arow_ok = (arow < M);

    const int bk  = tid >> 4;
    const int bn4 = (tid & 15) * 4;

    for (int k0 = 0; k0 < K; k0 += BK) {
        float4 a4 = make_float4(0.f, 0.f, 0.f, 0.f);
        if (arow_ok)
            a4 = *reinterpret_cast<const float4*>(&X[(size_t)arow * K + k0 + ac4]);
        As[ac4 + 0][ar] = a4.x;
        As[ac4 + 1][ar] = a4.y;
        As[ac4 + 2][ar] = a4.z;
        As[ac4 + 3][ar] = a4.w;

        float4 b4 = *reinterpret_cast<const float4*>(&W[(size_t)(k0 + bk) * Nout + col0 + bn4]);
        *reinterpret_cast<float4*>(&Bs[bk][bn4]) = b4;

        __syncthreads();
#pragma unroll
        for (int k = 0; k < BK; ++k) {
            float4 av = *reinterpret_cast<const float4*>(&As[k][ty * 4]);
            float4 bv = *reinterpret_cast<const float4*>(&Bs[k][tx * 4]);
            float a_[4] = {av.x, av.y, av.z, av.w};
            float b_[4] = {bv.x, bv.y, bv.z, bv.w};
#pragma unroll
            for (int i = 0; i < 4; ++i)
#pragma unroll
                for (int j = 0; j < 4; ++j)
                    acc[i][j] = fmaf(a_[i], b_[j], acc[i][j]);
        }
        __syncthreads();
    }

#pragma unroll
    for (int i = 0; i < 4; ++i) {
        int r = row0 + ty * 4 + i;
        if (r >= M) continue;
        float rsv = rs ? rs[r] : 1.0f;
#pragma unroll
        for (int j = 0; j < 4; ++j) {
            int c = col0 + tx * 4 + j;
            float v = acc[i][j] * rsv;
            if (bias) v += bias[c];
            if (act == 1) v = fmaxf(v, 0.0f);
            C[(size_t)r * Nout + c] = v;
        }
    }
}

// ---------------- CSR gather-aggregate + epilogue ----------------
// Y[d][:] = act( (A[d][:] + sum_{e in csr row d} A[csr_src[e]][:]) * dinv_in[d] + bias[:] )
// One wave per node. F==256 -> float4/lane; F==128 -> float2/lane.
// ACTMODE: 1 = relu, 2 = sigmoid + 1e-8
template <int F, int ACTMODE>
__global__ __launch_bounds__(256) void gather_nodes(
    const float* __restrict__ A, float* __restrict__ Y,
    const int* __restrict__ row_start, const int* __restrict__ csr_src,
    const float* __restrict__ dinv_in, const float* __restrict__ bias)
{
    constexpr int VEC = F / 64;
    const int wave = threadIdx.x >> 6;
    const int lane = threadIdx.x & 63;
    const int node = blockIdx.x * (256 >> 6) + wave;
    if (node >= NN) return;
    const int f0 = lane * VEC;

    float acc[VEC];
    {   // self-loop term
        const float* arow = A + (size_t)node * F + f0;
        if (VEC == 4) {
            float4 v = *reinterpret_cast<const float4*>(arow);
            acc[0] = v.x; acc[1] = v.y; acc[2] = v.z; acc[3] = v.w;
        } else {
            float2 v = *reinterpret_cast<const float2*>(arow);
            acc[0] = v.x; acc[1] = v.y;
        }
    }

    const int lo = row_start[node];
    const int hi = row_start[node + 1];
    for (int e = lo; e < hi; ++e) {
        int s = csr_src[e];
        const float* srow = A + (size_t)s * F + f0;
        if (VEC == 4) {
            float4 v = *reinterpret_cast<const float4*>(srow);
            acc[0] += v.x; acc[1] += v.y; acc[2] += v.z; acc[3] += v.w;
        } else {
            float2 v = *reinterpret_cast<const float2*>(srow);
            acc[0] += v.x; acc[1] += v.y;
        }
    }

    const float di = dinv_in[node];
    float* yrow = Y + (size_t)node * F + f0;
#pragma unroll
    for (int v = 0; v < VEC; ++v) {
        float x = acc[v] * di + bias[f0 + v];
        if (ACTMODE == 1) x = fmaxf(x, 0.0f);
        else              x = 1.0f / (1.0f + expf(-x)) + 1e-8f;
        acc[v] = x;
    }
    if (VEC == 4) *reinterpret_cast<float4*>(yrow) = make_float4(acc[0], acc[1], acc[2], acc[3]);
    else          *reinterpret_cast<float2*>(yrow) = make_float2(acc[0], acc[1]);
}

// ---------------- softmax over 64 logits, one wave per row ----------------
__global__ __launch_bounds__(256) void softmax64(const float* __restrict__ logits,
                                                 float* __restrict__ out, int n_rows)
{
    int wave = threadIdx.x >> 6;
    int lane = threadIdx.x & 63;
    int row  = blockIdx.x * 4 + wave;
    if (row >= n_rows) return;
    float v = logits[(size_t)row * 64 + lane];
    float m = v;
#pragma unroll
    for (int o = 32; o > 0; o >>= 1) m = fmaxf(m, __shfl_xor(m, o));
    float e = expf(v - m);
    float s = e;
#pragma unroll
    for (int o = 32; o > 0; o >>= 1) s += __shfl_xor(s, o);
    out[(size_t)row * 64 + lane] = e / s;
}

// ---------------- launcher ----------------
extern "C" void kernel_launch(void* const* d_in, const int* in_sizes, int n_in,
                              void* d_out, int out_size, void* d_ws, size_t ws_size,
                              hipStream_t stream)
{
    const float* x   = (const float*)d_in[0];
    const int*   src = (const int*)d_in[1];
    const int*   dst = (const int*)d_in[2];
    const float* Wg1 = (const float*)d_in[3];
    const float* bg1 = (const float*)d_in[4];
    const float* Wg2 = (const float*)d_in[5];
    const float* bg2 = (const float*)d_in[6];
    const float* Wg3 = (const float*)d_in[7];
    const float* bg3 = (const float*)d_in[8];
    const float* W1  = (const float*)d_in[9];
    const float* b1  = (const float*)d_in[10];
    const float* W2  = (const float*)d_in[11];
    const float* b2  = (const float*)d_in[12];
    const float* W3  = (const float*)d_in[13];
    const float* b3  = (const float*)d_in[14];

    float* out  = (float*)d_out;
    float* prob = out;                     // [N x 64]
    float* gnn  = out + (size_t)NN * ACT;  // [N x 128]

    float* ws       = (float*)d_ws;
    float* dinv_out = ws;                       // NN floats
    float* dinv_in  = ws + NN;                  // NN floats
    int*   cnt      = (int*)(ws + 2 * NN);      // NN ints (histogram, then reused only for dinv)
    int*   row_st   = (int*)(ws + 3 * NN);      // NN+1 ints
    int*   cursor   = (int*)(ws + 4 * NN + 16); // NN ints
    int*   csr_src  = (int*)(ws + 5 * NN + 32); // EE ints
    float* A        = ws + 5 * NN + 32 + EE + ((-(5 * NN + 32 + EE)) & 3); // align to 4 elems
    float* B        = A + (size_t)NN * 512;

    // --- degrees + CSR build ---
    init_deg_cnt<<<(NN + 255) / 256, 256, 0, stream>>>(dinv_out, cnt, NN);
    edge_deg<<<1024, 256, 0, stream>>>(src, dst, dinv_out, cnt, EE);
    deg_to_dinv<<<(NN + 255) / 256, 256, 0, stream>>>(dinv_out, dinv_in, cnt, NN);
    scan_csr<<<1, 1024, 0, stream>>>(cnt, row_st, cursor, NN);
    fill_csr<<<1024, 256, 0, stream>>>(src, dst, cursor, csr_src, EE);

    const int rb = (NN + BM - 1) / BM;   // 313 row tiles
    const int gb = (NN + 3) / 4;         // gather blocks: 4 nodes (waves) per block

    // --- GCN layer 1 ---
    gemm_f32<<<dim3(rb, HID / BN), 256, 0, stream>>>(x, Wg1, A, NN, OBS, HID, dinv_out, nullptr, 0);
    gather_nodes<HID, 1><<<gb, 256, 0, stream>>>(A, B, row_st, csr_src, dinv_in, bg1);

    // --- GCN layer 2 ---
    gemm_f32<<<dim3(rb, HID / BN), 256, 0, stream>>>(B, Wg2, A, NN, HID, HID, dinv_out, nullptr, 0);
    gather_nodes<HID, 1><<<gb, 256, 0, stream>>>(A, B, row_st, csr_src, dinv_in, bg2);

    // --- GCN layer 3 -> gnn_output (in d_out) ---
    gemm_f32<<<dim3(rb, EMB / BN), 256, 0, stream>>>(B, Wg3, A, NN, HID, EMB, dinv_out, nullptr, 0);
    gather_nodes<EMB, 2><<<gb, 256, 0, stream>>>(A, gnn, row_st, csr_src, dinv_in, bg3);

    // --- MLP ---
    gemm_f32<<<dim3(rb, MLPH / BN), 256, 0, stream>>>(gnn, W1, A, NN, EMB, MLPH, nullptr, b1, 1);
    gemm_f32<<<dim3(rb, MLPH / BN), 256, 0, stream>>>(A, W2, B, NN, MLPH, MLPH, nullptr, b2, 1);
    gemm_f32<<<dim3(rb, ACT / BN), 256, 0, stream>>>(B, W3, A, NN, MLPH, ACT, nullptr, b3, 0);

    // --- softmax ---
    softmax64<<<(NN + 3) / 4, 256, 0, stream>>>(A, prob, NN);
}

// Round 3
// 407.669 us; speedup vs baseline: 2.7139x; 1.4223x over previous
//
#include <hip/hip_runtime.h>
#include <hip/hip_bf16.h>
#include <math.h>

// Problem constants (match reference)
#define NN   20000
#define EE   320000
#define OBS  256
#define HID  256
#define EMB  128
#define MLPH 512
#define ACT  64

using short8 = __attribute__((ext_vector_type(8))) short;
using f32x4  = __attribute__((ext_vector_type(4))) float;

__device__ __forceinline__ unsigned short f2b(float v) {
    __hip_bfloat16 b = __float2bfloat16(v);
    return *reinterpret_cast<unsigned short*>(&b);
}
__device__ __forceinline__ float b2f(unsigned short u) {
    unsigned int x = ((unsigned int)u) << 16;
    return __uint_as_float(x);
}

// ---------------- degree / CSR-histogram kernels ----------------
__global__ void init_deg_cnt(float* __restrict__ dout, int* __restrict__ cnt, int n) {
    int i = blockIdx.x * blockDim.x + threadIdx.x;
    if (i < n) { dout[i] = 1.0f; cnt[i] = 0; }
}

__global__ void edge_deg(const int* __restrict__ src, const int* __restrict__ dst,
                         float* __restrict__ dout, int* __restrict__ cnt, int e) {
    for (int i = blockIdx.x * blockDim.x + threadIdx.x; i < e; i += gridDim.x * blockDim.x) {
        atomicAdd(&dout[src[i]], 1.0f);
        atomicAdd(&cnt[dst[i]], 1);
    }
}

__global__ void deg_to_dinv(float* __restrict__ dout, float* __restrict__ din,
                            const int* __restrict__ cnt, int n) {
    int i = blockIdx.x * blockDim.x + threadIdx.x;
    if (i < n) {
        dout[i] = rsqrtf(fmaxf(dout[i], 1.0f));
        din[i]  = rsqrtf((float)cnt[i] + 1.0f);
    }
}

__global__ __launch_bounds__(1024) void scan_csr(const int* __restrict__ cnt,
                                                 int* __restrict__ row_start,
                                                 int* __restrict__ cursor, int n)
{
    __shared__ int part[1024];
    const int t = threadIdx.x;
    const int chunk = (n + 1023) / 1024;
    const int lo = t * chunk;
    const int hi = min(lo + chunk, n);
    int s = 0;
    for (int i = lo; i < hi; ++i) s += cnt[i];
    part[t] = s;
    __syncthreads();
    for (int off = 1; off < 1024; off <<= 1) {
        int v = (t >= off) ? part[t - off] : 0;
        __syncthreads();
        part[t] += v;
        __syncthreads();
    }
    int run = (t == 0) ? 0 : part[t - 1];
    for (int i = lo; i < hi; ++i) {
        row_start[i] = run;
        cursor[i]    = run;
        run += cnt[i];
    }
    if (t == 1023) row_start[n] = part[1023];
}

__global__ void fill_csr(const int* __restrict__ src, const int* __restrict__ dst,
                         int* __restrict__ cursor, int* __restrict__ csr_src, int e)
{
    for (int i = blockIdx.x * blockDim.x + threadIdx.x; i < e; i += gridDim.x * blockDim.x) {
        int p = atomicAdd(&cursor[dst[i]], 1);
        csr_src[p] = src[i];
    }
}

// ---------------- conversions ----------------
__global__ void f32_to_bf16_vec(const float* __restrict__ X, unsigned short* __restrict__ Y, int n) {
    int i = (blockIdx.x * blockDim.x + threadIdx.x) * 4;
    if (i >= n) return;
    float4 v = *reinterpret_cast<const float4*>(&X[i]);
    Y[i + 0] = f2b(v.x); Y[i + 1] = f2b(v.y); Y[i + 2] = f2b(v.z); Y[i + 3] = f2b(v.w);
}

// W[K][N] f32 -> WT[N][K] bf16  (K, N multiples of 32)
__global__ void wt_bf16(const float* __restrict__ W, unsigned short* __restrict__ WT, int K, int N) {
    __shared__ float t[32][33];
    int k0 = blockIdx.x * 32, n0 = blockIdx.y * 32;
    int tx = threadIdx.x, ty = threadIdx.y;   // 32 x 8
    for (int i = 0; i < 32; i += 8)
        t[ty + i][tx] = W[(size_t)(k0 + ty + i) * N + (n0 + tx)];
    __syncthreads();
    for (int i = 0; i < 32; i += 8)
        WT[(size_t)(n0 + ty + i) * K + (k0 + tx)] = f2b(t[tx][ty + i]);
}

// ---------------- bf16 MFMA GEMM ----------------
// C[M x N] = act( rs[r] * (X[M x K] @ W[K x N]) + bias[c] ),  W given as WT[N][K]
// 128x128 tile, BK=32, 4 waves (2x2), each wave 64x64 via 4x4 frags of 16x16x32.
#define GBM 128
#define GBN 128
#define LDK 40   // padded LDS k-stride (bf16 elements) -> 80B row stride, 2-way bank alias only

__global__ __launch_bounds__(256) void gemm_bf16(
    const unsigned short* __restrict__ X, const unsigned short* __restrict__ WT,
    int M, int K, int N,
    const float* __restrict__ rs, const float* __restrict__ bias, int act,
    unsigned short* __restrict__ Ob, float* __restrict__ Of)
{
    __shared__ __align__(16) unsigned short Als[GBM * LDK];
    __shared__ __align__(16) unsigned short Bls[GBN * LDK];

    const int tid  = threadIdx.x;
    const int lane = tid & 63;
    const int wv   = tid >> 6;
    const int wm   = wv >> 1;
    const int wn   = wv & 1;
    const int row0 = blockIdx.x * GBM;
    const int col0 = blockIdx.y * GBN;

    const int srow = tid >> 2;        // 0..63 (staging row)
    const int skq  = (tid & 3) * 8;   // k-offset 0,8,16,24

    const int l15 = lane & 15;
    const int kro = (lane >> 4) * 8;

    f32x4 acc[4][4] = {};

    for (int k0 = 0; k0 < K; k0 += 32) {
#pragma unroll
        for (int rr = 0; rr < 2; ++rr) {
            int r  = srow + rr * 64;
            int gr = row0 + r;
            short8 va = {};
            if (gr < M) va = *reinterpret_cast<const short8*>(&X[(size_t)gr * K + k0 + skq]);
            *reinterpret_cast<short8*>(&Als[r * LDK + skq]) = va;
            int gn = col0 + r;
            short8 vb = {};
            if (gn < N) vb = *reinterpret_cast<const short8*>(&WT[(size_t)gn * K + k0 + skq]);
            *reinterpret_cast<short8*>(&Bls[r * LDK + skq]) = vb;
        }
        __syncthreads();

        short8 af[4], bfr[4];
#pragma unroll
        for (int mi = 0; mi < 4; ++mi)
            af[mi] = *reinterpret_cast<const short8*>(&Als[(wm * 64 + mi * 16 + l15) * LDK + kro]);
#pragma unroll
        for (int ni = 0; ni < 4; ++ni)
            bfr[ni] = *reinterpret_cast<const short8*>(&Bls[(wn * 64 + ni * 16 + l15) * LDK + kro]);
#pragma unroll
        for (int mi = 0; mi < 4; ++mi)
#pragma unroll
            for (int ni = 0; ni < 4; ++ni)
                acc[mi][ni] = __builtin_amdgcn_mfma_f32_16x16x32_bf16(af[mi], bfr[ni], acc[mi][ni], 0, 0, 0);
        __syncthreads();
    }

#pragma unroll
    for (int mi = 0; mi < 4; ++mi) {
#pragma unroll
        for (int q = 0; q < 4; ++q) {
            int r = row0 + wm * 64 + mi * 16 + (lane >> 4) * 4 + q;
            if (r >= M) continue;
            float rsv = rs ? rs[r] : 1.0f;
#pragma unroll
            for (int ni = 0; ni < 4; ++ni) {
                int c = col0 + wn * 64 + ni * 16 + l15;
                if (c >= N) continue;
                float v = acc[mi][ni][q] * rsv;
                if (bias) v += bias[c];
                if (act == 1) v = fmaxf(v, 0.0f);
                size_t idx = (size_t)r * N + c;
                if (Ob) Ob[idx] = f2b(v);
                if (Of) Of[idx] = v;
            }
        }
    }
}

// ---------------- CSR gather-aggregate + epilogue (bf16 in) ----------------
template <int F, int ACTMODE, bool OUTF32>
__global__ __launch_bounds__(256) void gather_bf16(
    const unsigned short* __restrict__ A, unsigned short* __restrict__ Yb,
    float* __restrict__ Yf,
    const int* __restrict__ row_start, const int* __restrict__ csr_src,
    const float* __restrict__ dinv_in, const float* __restrict__ bias)
{
    constexpr int VEC = F / 64;
    const int wave = threadIdx.x >> 6;
    const int lane = threadIdx.x & 63;
    const int node = blockIdx.x * 4 + wave;
    if (node >= NN) return;
    const int f0 = lane * VEC;

    float acc[VEC];
    {
        const unsigned short* ar = A + (size_t)node * F + f0;
        if (VEC == 4) {
            ushort4 u = *reinterpret_cast<const ushort4*>(ar);
            acc[0] = b2f(u.x); acc[1] = b2f(u.y); acc[2] = b2f(u.z); acc[3] = b2f(u.w);
        } else {
            ushort2 u = *reinterpret_cast<const ushort2*>(ar);
            acc[0] = b2f(u.x); acc[1] = b2f(u.y);
        }
    }
    const int lo = row_start[node];
    const int hi = row_start[node + 1];
    for (int e = lo; e < hi; ++e) {
        const unsigned short* sr = A + (size_t)csr_src[e] * F + f0;
        if (VEC == 4) {
            ushort4 u = *reinterpret_cast<const ushort4*>(sr);
            acc[0] += b2f(u.x); acc[1] += b2f(u.y); acc[2] += b2f(u.z); acc[3] += b2f(u.w);
        } else {
            ushort2 u = *reinterpret_cast<const ushort2*>(sr);
            acc[0] += b2f(u.x); acc[1] += b2f(u.y);
        }
    }

    const float di = dinv_in[node];
#pragma unroll
    for (int v = 0; v < VEC; ++v) {
        float xv = acc[v] * di + bias[f0 + v];
        if (ACTMODE == 1) xv = fmaxf(xv, 0.0f);
        else              xv = 1.0f / (1.0f + expf(-xv)) + 1e-8f;
        acc[v] = xv;
    }
    if (Yb) {
        unsigned short* yr = Yb + (size_t)node * F + f0;
        if (VEC == 4) {
            ushort4 u; u.x = f2b(acc[0]); u.y = f2b(acc[1]); u.z = f2b(acc[2]); u.w = f2b(acc[3]);
            *reinterpret_cast<ushort4*>(yr) = u;
        } else {
            ushort2 u; u.x = f2b(acc[0]); u.y = f2b(acc[1]);
            *reinterpret_cast<ushort2*>(yr) = u;
        }
    }
    if (OUTF32) {
        float* yf = Yf + (size_t)node * F + f0;
        if (VEC == 4) *reinterpret_cast<float4*>(yf) = make_float4(acc[0], acc[1], acc[2], acc[3]);
        else          *reinterpret_cast<float2*>(yf) = make_float2(acc[0], acc[1]);
    }
}

// ---------------- softmax over 64 logits, one wave per row ----------------
__global__ __launch_bounds__(256) void softmax64(const float* __restrict__ logits,
                                                 float* __restrict__ out, int n_rows)
{
    int wave = threadIdx.x >> 6;
    int lane = threadIdx.x & 63;
    int row  = blockIdx.x * 4 + wave;
    if (row >= n_rows) return;
    float v = logits[(size_t)row * 64 + lane];
    float m = v;
#pragma unroll
    for (int o = 32; o > 0; o >>= 1) m = fmaxf(m, __shfl_xor(m, o));
    float e = expf(v - m);
    float s = e;
#pragma unroll
    for (int o = 32; o > 0; o >>= 1) s += __shfl_xor(s, o);
    out[(size_t)row * 64 + lane] = e / s;
}

// ---------------- launcher ----------------
extern "C" void kernel_launch(void* const* d_in, const int* in_sizes, int n_in,
                              void* d_out, int out_size, void* d_ws, size_t ws_size,
                              hipStream_t stream)
{
    const float* x   = (const float*)d_in[0];
    const int*   src = (const int*)d_in[1];
    const int*   dst = (const int*)d_in[2];
    const float* Wg1 = (const float*)d_in[3];
    const float* bg1 = (const float*)d_in[4];
    const float* Wg2 = (const float*)d_in[5];
    const float* bg2 = (const float*)d_in[6];
    const float* Wg3 = (const float*)d_in[7];
    const float* bg3 = (const float*)d_in[8];
    const float* W1  = (const float*)d_in[9];
    const float* b1  = (const float*)d_in[10];
    const float* W2  = (const float*)d_in[11];
    const float* b2  = (const float*)d_in[12];
    const float* W3  = (const float*)d_in[13];
    const float* b3  = (const float*)d_in[14];

    float* out  = (float*)d_out;
    float* prob = out;                     // [N x 64]
    float* gnn  = out + (size_t)NN * ACT;  // [N x 128]

    // bump allocator over d_ws (256B aligned chunks)
    char* p = (char*)d_ws;
    auto alloc = [&](size_t bytes) { char* r = p; p += (bytes + 255) & ~(size_t)255; return r; };
    float*          dinv_out = (float*)alloc((size_t)NN * 4);
    float*          dinv_in  = (float*)alloc((size_t)NN * 4);
    int*            cnt      = (int*)alloc((size_t)NN * 4);
    int*            row_st   = (int*)alloc((size_t)(NN + 1) * 4);
    int*            cursor   = (int*)alloc((size_t)NN * 4);
    int*            csr_src  = (int*)alloc((size_t)EE * 4);
    unsigned short* xb       = (unsigned short*)alloc((size_t)NN * OBS * 2);
    unsigned short* WT1      = (unsigned short*)alloc((size_t)OBS * HID * 2);
    unsigned short* WT2      = (unsigned short*)alloc((size_t)HID * HID * 2);
    unsigned short* WT3      = (unsigned short*)alloc((size_t)HID * EMB * 2);
    unsigned short* WTm1     = (unsigned short*)alloc((size_t)EMB * MLPH * 2);
    unsigned short* WTm2     = (unsigned short*)alloc((size_t)MLPH * MLPH * 2);
    unsigned short* WTm3     = (unsigned short*)alloc((size_t)MLPH * ACT * 2);
    unsigned short* actA     = (unsigned short*)alloc((size_t)NN * 512 * 2);
    unsigned short* actB     = (unsigned short*)alloc((size_t)NN * 512 * 2);
    float*          logits   = (float*)alloc((size_t)NN * ACT * 4);

    // --- conversions (independent of graph work) ---
    f32_to_bf16_vec<<<(NN * OBS / 4 + 255) / 256, 256, 0, stream>>>(x, xb, NN * OBS);
    wt_bf16<<<dim3(OBS / 32, HID / 32),  dim3(32, 8), 0, stream>>>(Wg1, WT1, OBS, HID);
    wt_bf16<<<dim3(HID / 32, HID / 32),  dim3(32, 8), 0, stream>>>(Wg2, WT2, HID, HID);
    wt_bf16<<<dim3(HID / 32, EMB / 32),  dim3(32, 8), 0, stream>>>(Wg3, WT3, HID, EMB);
    wt_bf16<<<dim3(EMB / 32, MLPH / 32), dim3(32, 8), 0, stream>>>(W1, WTm1, EMB, MLPH);
    wt_bf16<<<dim3(MLPH / 32, MLPH / 32),dim3(32, 8), 0, stream>>>(W2, WTm2, MLPH, MLPH);
    wt_bf16<<<dim3(MLPH / 32, ACT / 32), dim3(32, 8), 0, stream>>>(W3, WTm3, MLPH, ACT);

    // --- degrees + CSR ---
    init_deg_cnt<<<(NN + 255) / 256, 256, 0, stream>>>(dinv_out, cnt, NN);
    edge_deg<<<1024, 256, 0, stream>>>(src, dst, dinv_out, cnt, EE);
    deg_to_dinv<<<(NN + 255) / 256, 256, 0, stream>>>(dinv_out, dinv_in, cnt, NN);
    scan_csr<<<1, 1024, 0, stream>>>(cnt, row_st, cursor, NN);
    fill_csr<<<1024, 256, 0, stream>>>(src, dst, cursor, csr_src, EE);

    const int rb = (NN + GBM - 1) / GBM;   // 157 row tiles
    const int gb = (NN + 3) / 4;

    // --- GCN layer 1 ---
    gemm_bf16<<<dim3(rb, HID / GBN), 256, 0, stream>>>(xb, WT1, NN, OBS, HID, dinv_out, nullptr, 0, actA, nullptr);
    gather_bf16<HID, 1, false><<<gb, 256, 0, stream>>>(actA, actB, nullptr, row_st, csr_src, dinv_in, bg1);

    // --- GCN layer 2 ---
    gemm_bf16<<<dim3(rb, HID / GBN), 256, 0, stream>>>(actB, WT2, NN, HID, HID, dinv_out, nullptr, 0, actA, nullptr);
    gather_bf16<HID, 1, false><<<gb, 256, 0, stream>>>(actA, actB, nullptr, row_st, csr_src, dinv_in, bg2);

    // --- GCN layer 3 -> gnn (f32, in d_out) + bf16 copy for MLP ---
    gemm_bf16<<<dim3(rb, 1), 256, 0, stream>>>(actB, WT3, NN, HID, EMB, dinv_out, nullptr, 0, actA, nullptr);
    gather_bf16<EMB, 2, true><<<gb, 256, 0, stream>>>(actA, actB, gnn, row_st, csr_src, dinv_in, bg3);

    // --- MLP ---
    gemm_bf16<<<dim3(rb, MLPH / GBN), 256, 0, stream>>>(actB, WTm1, NN, EMB, MLPH, nullptr, b1, 1, actA, nullptr);
    gemm_bf16<<<dim3(rb, MLPH / GBN), 256, 0, stream>>>(actA, WTm2, NN, MLPH, MLPH, nullptr, b2, 1, actB, nullptr);
    gemm_bf16<<<dim3(rb, 1), 256, 0, stream>>>(actB, WTm3, NN, MLPH, ACT, nullptr, b3, 0, nullptr, logits);

    // --- softmax ---
    softmax64<<<(NN + 3) / 4, 256, 0, stream>>>(logits, prob, NN);
}

// Round 4
// 330.806 us; speedup vs baseline: 3.3444x; 1.2323x over previous
//
#include <hip/hip_runtime.h>
#include <hip/hip_bf16.h>
#include <math.h>

// Problem constants (match reference)
#define NN   20000
#define EE   320000
#define OBS  256
#define HID  256
#define EMB  128
#define MLPH 512
#define ACT  64

using short8 = __attribute__((ext_vector_type(8))) short;
using f32x4  = __attribute__((ext_vector_type(4))) float;

__device__ __forceinline__ unsigned short f2b(float v) {
    __hip_bfloat16 b = __float2bfloat16(v);
    return *reinterpret_cast<unsigned short*>(&b);
}
__device__ __forceinline__ float b2f(unsigned short u) {
    return __uint_as_float(((unsigned int)u) << 16);
}

// ---------------- degree / CSR kernels ----------------
__global__ void edge_deg(const int* __restrict__ src, const int* __restrict__ dst,
                         int* __restrict__ cnt_out, int* __restrict__ cnt_in, int e) {
    for (int i = blockIdx.x * blockDim.x + threadIdx.x; i < e; i += gridDim.x * blockDim.x) {
        atomicAdd(&cnt_out[src[i]], 1);
        atomicAdd(&cnt_in[dst[i]], 1);
    }
}

// one-block scan: row_start/cursor from cnt_in; also dinv_in/dinv_out (self-loop adds 1 to both)
__global__ __launch_bounds__(1024) void scan_csr(const int* __restrict__ cnt_in,
                                                 const int* __restrict__ cnt_out,
                                                 int* __restrict__ row_start,
                                                 int* __restrict__ cursor,
                                                 float* __restrict__ dinv_in,
                                                 float* __restrict__ dinv_out, int n)
{
    __shared__ int part[1024];
    const int t = threadIdx.x;
    const int chunk = (n + 1023) / 1024;
    const int lo = t * chunk;
    const int hi = min(lo + chunk, n);
    int s = 0;
    for (int i = lo; i < hi; ++i) s += cnt_in[i];
    part[t] = s;
    __syncthreads();
    for (int off = 1; off < 1024; off <<= 1) {
        int v = (t >= off) ? part[t - off] : 0;
        __syncthreads();
        part[t] += v;
        __syncthreads();
    }
    int run = (t == 0) ? 0 : part[t - 1];
    for (int i = lo; i < hi; ++i) {
        row_start[i] = run;
        cursor[i]    = run;
        run += cnt_in[i];
        dinv_in[i]  = rsqrtf((float)(cnt_in[i] + 1));
        dinv_out[i] = rsqrtf((float)(cnt_out[i] + 1));
    }
    if (t == 1023) row_start[n] = part[1023];
}

__global__ void fill_csr(const int* __restrict__ src, const int* __restrict__ dst,
                         int* __restrict__ cursor, int* __restrict__ csr_src, int e)
{
    for (int i = blockIdx.x * blockDim.x + threadIdx.x; i < e; i += gridDim.x * blockDim.x) {
        int p = atomicAdd(&cursor[dst[i]], 1);
        csr_src[p] = src[i];
    }
}

// ---------------- conversions ----------------
__global__ void f32_to_bf16_vec(const float* __restrict__ X, unsigned short* __restrict__ Y, int n) {
    int i = (blockIdx.x * blockDim.x + threadIdx.x) * 4;
    if (i >= n) return;
    float4 v = *reinterpret_cast<const float4*>(&X[i]);
    Y[i + 0] = f2b(v.x); Y[i + 1] = f2b(v.y); Y[i + 2] = f2b(v.z); Y[i + 3] = f2b(v.w);
}

// all 6 weight transposes in one kernel. W[K][N] f32 -> WT[N][K] bf16.
__global__ void wt_all(const float* W0, const float* W1, const float* W2,
                       const float* W3, const float* W4, const float* W5,
                       unsigned short* T0, unsigned short* T1, unsigned short* T2,
                       unsigned short* T3, unsigned short* T4, unsigned short* T5)
{
    const float* W; unsigned short* T; int K, N;
    switch (blockIdx.y) {
        case 0: W = W0; T = T0; K = OBS;  N = HID;  break;
        case 1: W = W1; T = T1; K = HID;  N = HID;  break;
        case 2: W = W2; T = T2; K = HID;  N = EMB;  break;
        case 3: W = W3; T = T3; K = EMB;  N = MLPH; break;
        case 4: W = W4; T = T4; K = MLPH; N = MLPH; break;
        default: W = W5; T = T5; K = MLPH; N = ACT; break;
    }
    const int tk = K / 32, tn = N / 32;
    if (blockIdx.x >= tk * tn) return;
    const int k0 = (blockIdx.x % tk) * 32;
    const int n0 = (blockIdx.x / tk) * 32;
    __shared__ float t[32][33];
    const int tx = threadIdx.x, ty = threadIdx.y;  // 32 x 8
    for (int i = 0; i < 32; i += 8)
        t[ty + i][tx] = W[(size_t)(k0 + ty + i) * N + (n0 + tx)];
    __syncthreads();
    for (int i = 0; i < 32; i += 8)
        T[(size_t)(n0 + ty + i) * K + (k0 + tx)] = f2b(t[tx][ty + i]);
}

// ---------------- bf16 MFMA GEMM, 2-phase double-buffered global_load_lds ----------------
// C[M x N] = act( rs[r]*(X@W) + bias[c] ),  W given as WT[N][K].
// 128x128 tile, BK=32, 4 waves (2x2), per-wave 64x64 via 4x4 frags of 16x16x32.
// LDS: 2 bufs x (A 128x32 + B 128x32) bf16, linear 64B rows; chunk-XOR swizzle
// (chunk ^= row&3) applied via pre-swizzled GLOBAL source + swizzled ds_read.
#define GBM 128
#define GBN 128

__global__ __launch_bounds__(256) void gemm_bf16(
    const unsigned short* __restrict__ X, const unsigned short* __restrict__ WT,
    int M, int K, int N,
    const float* __restrict__ rs, const float* __restrict__ bias, int act,
    unsigned short* __restrict__ Ob, float* __restrict__ Of)
{
    __shared__ __align__(16) unsigned short lds[16384];  // 32 KB: [buf][A/B][128 rows][32]

    const int tid  = threadIdx.x;
    const int lane = tid & 63;
    const int wv   = tid >> 6;
    const int wm   = wv >> 1;
    const int wn   = wv & 1;
    const int row0 = blockIdx.x * GBM;
    const int col0 = blockIdx.y * GBN;

    // staging: round rr covers rows rr*64 + wv*16 + (lane>>2), physical chunk lane&3
    const int strow  = lane >> 2;                       // 0..15
    const int schunk = (lane & 3) ^ (strow & 3);        // pre-swizzled source chunk

    const int l15 = lane & 15;
    const int kc  = lane >> 4;                          // logical k-chunk 0..3

    f32x4 acc[4][4] = {};

    auto stage = [&](int buf, int k0) {
#pragma unroll
        for (int rr = 0; rr < 2; ++rr) {
            int r  = rr * 64 + wv * 16 + strow;
            int gr = min(row0 + r, M - 1);
            const unsigned short* srcA = X + (size_t)gr * K + k0 + schunk * 8;
            unsigned short* dstA = &lds[buf * 8192 + rr * 2048 + wv * 512];
            __builtin_amdgcn_global_load_lds(
                (const __attribute__((address_space(1))) void*)srcA,
                (__attribute__((address_space(3))) void*)dstA, 16, 0, 0);
        }
#pragma unroll
        for (int rr = 0; rr < 2; ++rr) {
            int r  = rr * 64 + wv * 16 + strow;
            int gn = min(col0 + r, N - 1);
            const unsigned short* srcB = WT + (size_t)gn * K + k0 + schunk * 8;
            unsigned short* dstB = &lds[buf * 8192 + 4096 + rr * 2048 + wv * 512];
            __builtin_amdgcn_global_load_lds(
                (const __attribute__((address_space(1))) void*)srcB,
                (__attribute__((address_space(3))) void*)dstB, 16, 0, 0);
        }
    };

    const int nt = K >> 5;
    int cur = 0;
    stage(0, 0);
    for (int t = 0; t < nt; ++t) {
        if (t + 1 < nt) {
            stage(cur ^ 1, (t + 1) << 5);
            asm volatile("s_waitcnt vmcnt(4)" ::: "memory");
        } else {
            asm volatile("s_waitcnt vmcnt(0)" ::: "memory");
        }
        __builtin_amdgcn_s_barrier();
        __builtin_amdgcn_sched_barrier(0);

        short8 af[4], bfr[4];
#pragma unroll
        for (int mi = 0; mi < 4; ++mi) {
            int fr = wm * 64 + mi * 16 + l15;
            int pc = kc ^ (fr & 3);
            af[mi] = *reinterpret_cast<const short8*>(&lds[cur * 8192 + fr * 32 + pc * 8]);
        }
#pragma unroll
        for (int ni = 0; ni < 4; ++ni) {
            int fn = wn * 64 + ni * 16 + l15;
            int pc = kc ^ (fn & 3);
            bfr[ni] = *reinterpret_cast<const short8*>(&lds[cur * 8192 + 4096 + fn * 32 + pc * 8]);
        }
#pragma unroll
        for (int mi = 0; mi < 4; ++mi)
#pragma unroll
            for (int ni = 0; ni < 4; ++ni)
                acc[mi][ni] = __builtin_amdgcn_mfma_f32_16x16x32_bf16(af[mi], bfr[ni], acc[mi][ni], 0, 0, 0);

        __builtin_amdgcn_s_barrier();
        cur ^= 1;
    }

    if (act == 3) {
        // fused softmax epilogue (N == 64: all cols live in wn==0 fragments)
        if (wn == 1) return;
#pragma unroll
        for (int mi = 0; mi < 4; ++mi) {
#pragma unroll
            for (int q = 0; q < 4; ++q) {
                int r = row0 + wm * 64 + mi * 16 + (lane >> 4) * 4 + q;
                if (r >= M) continue;
                float v[4];
                float mx = -1e30f;
#pragma unroll
                for (int ni = 0; ni < 4; ++ni) {
                    v[ni] = acc[mi][ni][q] + bias[ni * 16 + l15];
                    mx = fmaxf(mx, v[ni]);
                }
#pragma unroll
                for (int o = 8; o >= 1; o >>= 1) mx = fmaxf(mx, __shfl_xor(mx, o));
                float s = 0.0f;
#pragma unroll
                for (int ni = 0; ni < 4; ++ni) { v[ni] = expf(v[ni] - mx); s += v[ni]; }
#pragma unroll
                for (int o = 8; o >= 1; o >>= 1) s += __shfl_xor(s, o);
                float inv = 1.0f / s;
#pragma unroll
                for (int ni = 0; ni < 4; ++ni)
                    Of[(size_t)r * 64 + ni * 16 + l15] = v[ni] * inv;
            }
        }
        return;
    }

#pragma unroll
    for (int mi = 0; mi < 4; ++mi) {
#pragma unroll
        for (int q = 0; q < 4; ++q) {
            int r = row0 + wm * 64 + mi * 16 + (lane >> 4) * 4 + q;
            if (r >= M) continue;
            float rsv = rs ? rs[r] : 1.0f;
#pragma unroll
            for (int ni = 0; ni < 4; ++ni) {
                int c = col0 + wn * 64 + ni * 16 + l15;
                if (c >= N) continue;
                float v = acc[mi][ni][q] * rsv;
                if (bias) v += bias[c];
                if (act == 1) v = fmaxf(v, 0.0f);
                size_t idx = (size_t)r * N + c;
                if (Ob) Ob[idx] = f2b(v);
                if (Of) Of[idx] = v;
            }
        }
    }
}

// ---------------- CSR gather-aggregate + epilogue (bf16 in), 4-deep unrolled ----------------
template <int F, int ACTMODE, bool OUTF32>
__global__ __launch_bounds__(256) void gather_bf16(
    const unsigned short* __restrict__ A, unsigned short* __restrict__ Yb,
    float* __restrict__ Yf,
    const int* __restrict__ row_start, const int* __restrict__ csr_src,
    const float* __restrict__ dinv_in, const float* __restrict__ bias)
{
    constexpr int VEC = F / 64;
    const int wave = threadIdx.x >> 6;
    const int lane = threadIdx.x & 63;
    const int node = blockIdx.x * 4 + wave;
    if (node >= NN) return;
    const int f0 = lane * VEC;

    float acc[VEC];
    {
        const unsigned short* ar = A + (size_t)node * F + f0;
        if (VEC == 4) {
            ushort4 u = *reinterpret_cast<const ushort4*>(ar);
            acc[0] = b2f(u.x); acc[1] = b2f(u.y); acc[2] = b2f(u.z); acc[3] = b2f(u.w);
        } else {
            ushort2 u = *reinterpret_cast<const ushort2*>(ar);
            acc[0] = b2f(u.x); acc[1] = b2f(u.y);
        }
    }
    const int lo = row_start[node];
    const int hi = row_start[node + 1];
    int e = lo;
    const int n4 = lo + ((hi - lo) & ~3);
    for (; e < n4; e += 4) {
        int s0 = csr_src[e + 0], s1 = csr_src[e + 1];
        int s2 = csr_src[e + 2], s3 = csr_src[e + 3];
        if (VEC == 4) {
            ushort4 u0 = *reinterpret_cast<const ushort4*>(A + (size_t)s0 * F + f0);
            ushort4 u1 = *reinterpret_cast<const ushort4*>(A + (size_t)s1 * F + f0);
            ushort4 u2 = *reinterpret_cast<const ushort4*>(A + (size_t)s2 * F + f0);
            ushort4 u3 = *reinterpret_cast<const ushort4*>(A + (size_t)s3 * F + f0);
            acc[0] += b2f(u0.x) + b2f(u1.x) + b2f(u2.x) + b2f(u3.x);
            acc[1] += b2f(u0.y) + b2f(u1.y) + b2f(u2.y) + b2f(u3.y);
            acc[2] += b2f(u0.z) + b2f(u1.z) + b2f(u2.z) + b2f(u3.z);
            acc[3] += b2f(u0.w) + b2f(u1.w) + b2f(u2.w) + b2f(u3.w);
        } else {
            ushort2 u0 = *reinterpret_cast<const ushort2*>(A + (size_t)s0 * F + f0);
            ushort2 u1 = *reinterpret_cast<const ushort2*>(A + (size_t)s1 * F + f0);
            ushort2 u2 = *reinterpret_cast<const ushort2*>(A + (size_t)s2 * F + f0);
            ushort2 u3 = *reinterpret_cast<const ushort2*>(A + (size_t)s3 * F + f0);
            acc[0] += b2f(u0.x) + b2f(u1.x) + b2f(u2.x) + b2f(u3.x);
            acc[1] += b2f(u0.y) + b2f(u1.y) + b2f(u2.y) + b2f(u3.y);
        }
    }
    for (; e < hi; ++e) {
        const unsigned short* sr = A + (size_t)csr_src[e] * F + f0;
        if (VEC == 4) {
            ushort4 u = *reinterpret_cast<const ushort4*>(sr);
            acc[0] += b2f(u.x); acc[1] += b2f(u.y); acc[2] += b2f(u.z); acc[3] += b2f(u.w);
        } else {
            ushort2 u = *reinterpret_cast<const ushort2*>(sr);
            acc[0] += b2f(u.x); acc[1] += b2f(u.y);
        }
    }

    const float di = dinv_in[node];
#pragma unroll
    for (int v = 0; v < VEC; ++v) {
        float xv = acc[v] * di + bias[f0 + v];
        if (ACTMODE == 1) xv = fmaxf(xv, 0.0f);
        else              xv = 1.0f / (1.0f + expf(-xv)) + 1e-8f;
        acc[v] = xv;
    }
    if (Yb) {
        unsigned short* yr = Yb + (size_t)node * F + f0;
        if (VEC == 4) {
            ushort4 u; u.x = f2b(acc[0]); u.y = f2b(acc[1]); u.z = f2b(acc[2]); u.w = f2b(acc[3]);
            *reinterpret_cast<ushort4*>(yr) = u;
        } else {
            ushort2 u; u.x = f2b(acc[0]); u.y = f2b(acc[1]);
            *reinterpret_cast<ushort2*>(yr) = u;
        }
    }
    if (OUTF32) {
        float* yf = Yf + (size_t)node * F + f0;
        if (VEC == 4) *reinterpret_cast<float4*>(yf) = make_float4(acc[0], acc[1], acc[2], acc[3]);
        else          *reinterpret_cast<float2*>(yf) = make_float2(acc[0], acc[1]);
    }
}

// ---------------- launcher ----------------
extern "C" void kernel_launch(void* const* d_in, const int* in_sizes, int n_in,
                              void* d_out, int out_size, void* d_ws, size_t ws_size,
                              hipStream_t stream)
{
    const float* x   = (const float*)d_in[0];
    const int*   src = (const int*)d_in[1];
    const int*   dst = (const int*)d_in[2];
    const float* Wg1 = (const float*)d_in[3];
    const float* bg1 = (const float*)d_in[4];
    const float* Wg2 = (const float*)d_in[5];
    const float* bg2 = (const float*)d_in[6];
    const float* Wg3 = (const float*)d_in[7];
    const float* bg3 = (const float*)d_in[8];
    const float* W1  = (const float*)d_in[9];
    const float* b1  = (const float*)d_in[10];
    const float* W2  = (const float*)d_in[11];
    const float* b2  = (const float*)d_in[12];
    const float* W3  = (const float*)d_in[13];
    const float* b3  = (const float*)d_in[14];

    float* out  = (float*)d_out;
    float* prob = out;                     // [N x 64]
    float* gnn  = out + (size_t)NN * ACT;  // [N x 128]

    char* p = (char*)d_ws;
    auto alloc = [&](size_t bytes) { char* r = p; p += (bytes + 255) & ~(size_t)255; return r; };
    float*          dinv_out = (float*)alloc((size_t)NN * 4);
    float*          dinv_in  = (float*)alloc((size_t)NN * 4);
    int*            cnt2     = (int*)alloc((size_t)2 * NN * 4);   // [cnt_in | cnt_out]
    int*            row_st   = (int*)alloc((size_t)(NN + 1) * 4);
    int*            cursor   = (int*)alloc((size_t)NN * 4);
    int*            csr_src  = (int*)alloc((size_t)EE * 4);
    unsigned short* xb       = (unsigned short*)alloc((size_t)NN * OBS * 2);
    unsigned short* WT1      = (unsigned short*)alloc((size_t)HID * OBS * 2);
    unsigned short* WT2      = (unsigned short*)alloc((size_t)HID * HID * 2);
    unsigned short* WT3      = (unsigned short*)alloc((size_t)EMB * HID * 2);
    unsigned short* WTm1     = (unsigned short*)alloc((size_t)MLPH * EMB * 2);
    unsigned short* WTm2     = (unsigned short*)alloc((size_t)MLPH * MLPH * 2);
    unsigned short* WTm3     = (unsigned short*)alloc((size_t)ACT * MLPH * 2);
    unsigned short* actA     = (unsigned short*)alloc((size_t)NN * 512 * 2);
    unsigned short* actB     = (unsigned short*)alloc((size_t)NN * 512 * 2);

    int* cnt_in  = cnt2;
    int* cnt_out = cnt2 + NN;

    // --- conversions ---
    f32_to_bf16_vec<<<(NN * OBS / 4 + 255) / 256, 256, 0, stream>>>(x, xb, NN * OBS);
    wt_all<<<dim3(256, 6), dim3(32, 8), 0, stream>>>(Wg1, Wg2, Wg3, W1, W2, W3,
                                                     WT1, WT2, WT3, WTm1, WTm2, WTm3);

    // --- degrees + CSR ---
    hipMemsetAsync(cnt2, 0, (size_t)2 * NN * 4, stream);
    edge_deg<<<1024, 256, 0, stream>>>(src, dst, cnt_out, cnt_in, EE);
    scan_csr<<<1, 1024, 0, stream>>>(cnt_in, cnt_out, row_st, cursor, dinv_in, dinv_out, NN);
    fill_csr<<<1024, 256, 0, stream>>>(src, dst, cursor, csr_src, EE);

    const int rb = (NN + GBM - 1) / GBM;   // 157 row tiles
    const int gb = (NN + 3) / 4;

    // --- GCN layer 1 ---
    gemm_bf16<<<dim3(rb, HID / GBN), 256, 0, stream>>>(xb, WT1, NN, OBS, HID, dinv_out, nullptr, 0, actA, nullptr);
    gather_bf16<HID, 1, false><<<gb, 256, 0, stream>>>(actA, actB, nullptr, row_st, csr_src, dinv_in, bg1);

    // --- GCN layer 2 ---
    gemm_bf16<<<dim3(rb, HID / GBN), 256, 0, stream>>>(actB, WT2, NN, HID, HID, dinv_out, nullptr, 0, actA, nullptr);
    gather_bf16<HID, 1, false><<<gb, 256, 0, stream>>>(actA, actB, nullptr, row_st, csr_src, dinv_in, bg2);

    // --- GCN layer 3 -> gnn (f32, in d_out) + bf16 copy for MLP ---
    gemm_bf16<<<dim3(rb, 1), 256, 0, stream>>>(actB, WT3, NN, HID, EMB, dinv_out, nullptr, 0, actA, nullptr);
    gather_bf16<EMB, 2, true><<<gb, 256, 0, stream>>>(actA, actB, gnn, row_st, csr_src, dinv_in, bg3);

    // --- MLP (softmax fused into last GEMM) ---
    gemm_bf16<<<dim3(rb, MLPH / GBN), 256, 0, stream>>>(actB, WTm1, NN, EMB, MLPH, nullptr, b1, 1, actA, nullptr);
    gemm_bf16<<<dim3(rb, MLPH / GBN), 256, 0, stream>>>(actA, WTm2, NN, MLPH, MLPH, nullptr, b2, 1, actB, nullptr);
    gemm_bf16<<<dim3(rb, 1), 256, 0, stream>>>(actB, WTm3, NN, MLPH, ACT, nullptr, b3, 3, nullptr, prob);
}

// Round 5
// 273.471 us; speedup vs baseline: 4.0456x; 1.2097x over previous
//
#include <hip/hip_runtime.h>
#include <hip/hip_bf16.h>
#include <math.h>

// Problem constants (match reference)
#define NN   20000
#define EE   320000
#define OBS  256
#define HID  256
#define EMB  128
#define MLPH 512
#define ACT  64

#define SCAN_NB ((NN + 255) / 256)   // 79 scan blocks

using short8 = __attribute__((ext_vector_type(8))) short;
using f32x4  = __attribute__((ext_vector_type(4))) float;

__device__ __forceinline__ unsigned short f2b(float v) {
    __hip_bfloat16 b = __float2bfloat16(v);
    return *reinterpret_cast<unsigned short*>(&b);
}
__device__ __forceinline__ float b2f(unsigned short u) {
    return __uint_as_float(((unsigned int)u) << 16);
}

// ---------------- degree / CSR kernels ----------------
__global__ void edge_deg(const int* __restrict__ src, const int* __restrict__ dst,
                         int* __restrict__ cnt_out, int* __restrict__ cnt_in, int e) {
    for (int i = blockIdx.x * blockDim.x + threadIdx.x; i < e; i += gridDim.x * blockDim.x) {
        atomicAdd(&cnt_out[src[i]], 1);
        atomicAdd(&cnt_in[dst[i]], 1);
    }
}

// phase 1: per-block partial sums of cnt_in + dinv computation (fully parallel)
__global__ __launch_bounds__(256) void csr_partials(
    const int* __restrict__ cnt_in, const int* __restrict__ cnt_out,
    int* __restrict__ partial, float* __restrict__ dinv_in, float* __restrict__ dinv_out)
{
    const int i = blockIdx.x * 256 + threadIdx.x;
    int v = 0;
    if (i < NN) {
        v = cnt_in[i];
        dinv_in[i]  = rsqrtf((float)(v + 1));
        dinv_out[i] = rsqrtf((float)(cnt_out[i] + 1));
    }
    int s = v;
#pragma unroll
    for (int o = 32; o >= 1; o >>= 1) s += __shfl_xor(s, o);
    __shared__ int ws[4];
    const int lane = threadIdx.x & 63, wv = threadIdx.x >> 6;
    if (lane == 0) ws[wv] = s;
    __syncthreads();
    if (threadIdx.x == 0) partial[blockIdx.x] = ws[0] + ws[1] + ws[2] + ws[3];
}

// phase 2: exclusive scan of the 79 partials (one small block)
__global__ __launch_bounds__(128) void scan_partials(int* __restrict__ partial,
                                                     int* __restrict__ row_start)
{
    __shared__ int t[128];
    const int tid = threadIdx.x;
    int v = (tid < SCAN_NB) ? partial[tid] : 0;
    t[tid] = v;
    __syncthreads();
    for (int off = 1; off < 128; off <<= 1) {
        int u = (tid >= off) ? t[tid - off] : 0;
        __syncthreads();
        t[tid] += u;
        __syncthreads();
    }
    if (tid < SCAN_NB) partial[tid] = t[tid] - v;   // exclusive
    if (tid == 0) row_start[NN] = EE;               // total edges is a constant
}

// phase 3: block-local exclusive scan + block offset -> row_start, cursor (coalesced)
__global__ __launch_bounds__(256) void csr_scan_write(
    const int* __restrict__ cnt_in, const int* __restrict__ partial,
    int* __restrict__ row_start, int* __restrict__ cursor)
{
    const int b = blockIdx.x;
    const int i = b * 256 + threadIdx.x;
    const int lane = threadIdx.x & 63, wv = threadIdx.x >> 6;
    int v = (i < NN) ? cnt_in[i] : 0;
    int x = v;
#pragma unroll
    for (int o = 1; o < 64; o <<= 1) {
        int u = __shfl_up(x, o);
        if (lane >= o) x += u;
    }
    __shared__ int wsum[4];
    if (lane == 63) wsum[wv] = x;
    __syncthreads();
    int wadd = 0;
    for (int w = 0; w < wv; ++w) wadd += wsum[w];
    const int excl = x - v + wadd + partial[b];
    if (i < NN) { row_start[i] = excl; cursor[i] = excl; }
}

__global__ void fill_csr(const int* __restrict__ src, const int* __restrict__ dst,
                         int* __restrict__ cursor, int* __restrict__ csr_src, int e)
{
    for (int i = blockIdx.x * blockDim.x + threadIdx.x; i < e; i += gridDim.x * blockDim.x) {
        int p = atomicAdd(&cursor[dst[i]], 1);
        csr_src[p] = src[i];
    }
}

// ---------------- conversions ----------------
__global__ void f32_to_bf16_vec(const float* __restrict__ X, unsigned short* __restrict__ Y, int n) {
    int i = (blockIdx.x * blockDim.x + threadIdx.x) * 4;
    if (i >= n) return;
    float4 v = *reinterpret_cast<const float4*>(&X[i]);
    Y[i + 0] = f2b(v.x); Y[i + 1] = f2b(v.y); Y[i + 2] = f2b(v.z); Y[i + 3] = f2b(v.w);
}

// all 6 weight transposes in one kernel. W[K][N] f32 -> WT[N][K] bf16.
__global__ void wt_all(const float* W0, const float* W1, const float* W2,
                       const float* W3, const float* W4, const float* W5,
                       unsigned short* T0, unsigned short* T1, unsigned short* T2,
                       unsigned short* T3, unsigned short* T4, unsigned short* T5)
{
    const float* W; unsigned short* T; int K, N;
    switch (blockIdx.y) {
        case 0: W = W0; T = T0; K = OBS;  N = HID;  break;
        case 1: W = W1; T = T1; K = HID;  N = HID;  break;
        case 2: W = W2; T = T2; K = HID;  N = EMB;  break;
        case 3: W = W3; T = T3; K = EMB;  N = MLPH; break;
        case 4: W = W4; T = T4; K = MLPH; N = MLPH; break;
        default: W = W5; T = T5; K = MLPH; N = ACT; break;
    }
    const int tk = K / 32, tn = N / 32;
    if (blockIdx.x >= tk * tn) return;
    const int k0 = (blockIdx.x % tk) * 32;
    const int n0 = (blockIdx.x / tk) * 32;
    __shared__ float t[32][33];
    const int tx = threadIdx.x, ty = threadIdx.y;  // 32 x 8
    for (int i = 0; i < 32; i += 8)
        t[ty + i][tx] = W[(size_t)(k0 + ty + i) * N + (n0 + tx)];
    __syncthreads();
    for (int i = 0; i < 32; i += 8)
        T[(size_t)(n0 + ty + i) * K + (k0 + tx)] = f2b(t[tx][ty + i]);
}

// ---------------- bf16 MFMA GEMM, 2-phase double-buffered global_load_lds ----------------
// C[M x N] = act( rs[r]*(X@W) + bias[c] ),  W given as WT[N][K].
// 128x128 tile, BK=32, 4 waves (2x2), per-wave 64x64 via 4x4 frags of 16x16x32.
// LDS: 2 bufs x (A 128x32 + B 128x32) bf16, linear 64B rows; chunk-XOR swizzle
// (chunk ^= row&3) applied via pre-swizzled GLOBAL source + swizzled ds_read.
#define GBM 128
#define GBN 128

__global__ __launch_bounds__(256) void gemm_bf16(
    const unsigned short* __restrict__ X, const unsigned short* __restrict__ WT,
    int M, int K, int N,
    const float* __restrict__ rs, const float* __restrict__ bias, int act,
    unsigned short* __restrict__ Ob, float* __restrict__ Of)
{
    __shared__ __align__(16) unsigned short lds[16384];  // 32 KB: [buf][A/B][128 rows][32]

    const int tid  = threadIdx.x;
    const int lane = tid & 63;
    const int wv   = tid >> 6;
    const int wm   = wv >> 1;
    const int wn   = wv & 1;
    const int row0 = blockIdx.x * GBM;
    const int col0 = blockIdx.y * GBN;

    // staging: round rr covers rows rr*64 + wv*16 + (lane>>2), physical chunk lane&3
    const int strow  = lane >> 2;                       // 0..15
    const int schunk = (lane & 3) ^ (strow & 3);        // pre-swizzled source chunk

    const int l15 = lane & 15;
    const int kc  = lane >> 4;                          // logical k-chunk 0..3

    f32x4 acc[4][4] = {};

    auto stage = [&](int buf, int k0) {
#pragma unroll
        for (int rr = 0; rr < 2; ++rr) {
            int r  = rr * 64 + wv * 16 + strow;
            int gr = min(row0 + r, M - 1);
            const unsigned short* srcA = X + (size_t)gr * K + k0 + schunk * 8;
            unsigned short* dstA = &lds[buf * 8192 + rr * 2048 + wv * 512];
            __builtin_amdgcn_global_load_lds(
                (const __attribute__((address_space(1))) void*)srcA,
                (__attribute__((address_space(3))) void*)dstA, 16, 0, 0);
        }
#pragma unroll
        for (int rr = 0; rr < 2; ++rr) {
            int r  = rr * 64 + wv * 16 + strow;
            int gn = min(col0 + r, N - 1);
            const unsigned short* srcB = WT + (size_t)gn * K + k0 + schunk * 8;
            unsigned short* dstB = &lds[buf * 8192 + 4096 + rr * 2048 + wv * 512];
            __builtin_amdgcn_global_load_lds(
                (const __attribute__((address_space(1))) void*)srcB,
                (__attribute__((address_space(3))) void*)dstB, 16, 0, 0);
        }
    };

    const int nt = K >> 5;
    int cur = 0;
    stage(0, 0);
    for (int t = 0; t < nt; ++t) {
        if (t + 1 < nt) {
            stage(cur ^ 1, (t + 1) << 5);
            asm volatile("s_waitcnt vmcnt(4)" ::: "memory");
        } else {
            asm volatile("s_waitcnt vmcnt(0)" ::: "memory");
        }
        __builtin_amdgcn_s_barrier();
        __builtin_amdgcn_sched_barrier(0);

        short8 af[4], bfr[4];
#pragma unroll
        for (int mi = 0; mi < 4; ++mi) {
            int fr = wm * 64 + mi * 16 + l15;
            int pc = kc ^ (fr & 3);
            af[mi] = *reinterpret_cast<const short8*>(&lds[cur * 8192 + fr * 32 + pc * 8]);
        }
#pragma unroll
        for (int ni = 0; ni < 4; ++ni) {
            int fn = wn * 64 + ni * 16 + l15;
            int pc = kc ^ (fn & 3);
            bfr[ni] = *reinterpret_cast<const short8*>(&lds[cur * 8192 + 4096 + fn * 32 + pc * 8]);
        }
#pragma unroll
        for (int mi = 0; mi < 4; ++mi)
#pragma unroll
            for (int ni = 0; ni < 4; ++ni)
                acc[mi][ni] = __builtin_amdgcn_mfma_f32_16x16x32_bf16(af[mi], bfr[ni], acc[mi][ni], 0, 0, 0);

        __builtin_amdgcn_s_barrier();
        cur ^= 1;
    }

    if (act == 3) {
        // fused softmax epilogue (N == 64: all cols live in wn==0 fragments)
        if (wn == 1) return;
#pragma unroll
        for (int mi = 0; mi < 4; ++mi) {
#pragma unroll
            for (int q = 0; q < 4; ++q) {
                int r = row0 + wm * 64 + mi * 16 + (lane >> 4) * 4 + q;
                if (r >= M) continue;
                float v[4];
                float mx = -1e30f;
#pragma unroll
                for (int ni = 0; ni < 4; ++ni) {
                    v[ni] = acc[mi][ni][q] + bias[ni * 16 + l15];
                    mx = fmaxf(mx, v[ni]);
                }
#pragma unroll
                for (int o = 8; o >= 1; o >>= 1) mx = fmaxf(mx, __shfl_xor(mx, o));
                float s = 0.0f;
#pragma unroll
                for (int ni = 0; ni < 4; ++ni) { v[ni] = expf(v[ni] - mx); s += v[ni]; }
#pragma unroll
                for (int o = 8; o >= 1; o >>= 1) s += __shfl_xor(s, o);
                float inv = 1.0f / s;
#pragma unroll
                for (int ni = 0; ni < 4; ++ni)
                    Of[(size_t)r * 64 + ni * 16 + l15] = v[ni] * inv;
            }
        }
        return;
    }

#pragma unroll
    for (int mi = 0; mi < 4; ++mi) {
#pragma unroll
        for (int q = 0; q < 4; ++q) {
            int r = row0 + wm * 64 + mi * 16 + (lane >> 4) * 4 + q;
            if (r >= M) continue;
            float rsv = rs ? rs[r] : 1.0f;
#pragma unroll
            for (int ni = 0; ni < 4; ++ni) {
                int c = col0 + wn * 64 + ni * 16 + l15;
                if (c >= N) continue;
                float v = acc[mi][ni][q] * rsv;
                if (bias) v += bias[c];
                if (act == 1) v = fmaxf(v, 0.0f);
                size_t idx = (size_t)r * N + c;
                if (Ob) Ob[idx] = f2b(v);
                if (Of) Of[idx] = v;
            }
        }
    }
}

// ---------------- CSR gather-aggregate + epilogue (bf16 in), 4-deep unrolled ----------------
template <int F, int ACTMODE, bool OUTF32>
__global__ __launch_bounds__(256) void gather_bf16(
    const unsigned short* __restrict__ A, unsigned short* __restrict__ Yb,
    float* __restrict__ Yf,
    const int* __restrict__ row_start, const int* __restrict__ csr_src,
    const float* __restrict__ dinv_in, const float* __restrict__ bias)
{
    constexpr int VEC = F / 64;
    const int wave = threadIdx.x >> 6;
    const int lane = threadIdx.x & 63;
    const int node = blockIdx.x * 4 + wave;
    if (node >= NN) return;
    const int f0 = lane * VEC;

    float acc[VEC];
    {
        const unsigned short* ar = A + (size_t)node * F + f0;
        if (VEC == 4) {
            ushort4 u = *reinterpret_cast<const ushort4*>(ar);
            acc[0] = b2f(u.x); acc[1] = b2f(u.y); acc[2] = b2f(u.z); acc[3] = b2f(u.w);
        } else {
            ushort2 u = *reinterpret_cast<const ushort2*>(ar);
            acc[0] = b2f(u.x); acc[1] = b2f(u.y);
        }
    }
    const int lo = row_start[node];
    const int hi = row_start[node + 1];
    int e = lo;
    const int n4 = lo + ((hi - lo) & ~3);
    for (; e < n4; e += 4) {
        int s0 = csr_src[e + 0], s1 = csr_src[e + 1];
        int s2 = csr_src[e + 2], s3 = csr_src[e + 3];
        if (VEC == 4) {
            ushort4 u0 = *reinterpret_cast<const ushort4*>(A + (size_t)s0 * F + f0);
            ushort4 u1 = *reinterpret_cast<const ushort4*>(A + (size_t)s1 * F + f0);
            ushort4 u2 = *reinterpret_cast<const ushort4*>(A + (size_t)s2 * F + f0);
            ushort4 u3 = *reinterpret_cast<const ushort4*>(A + (size_t)s3 * F + f0);
            acc[0] += b2f(u0.x) + b2f(u1.x) + b2f(u2.x) + b2f(u3.x);
            acc[1] += b2f(u0.y) + b2f(u1.y) + b2f(u2.y) + b2f(u3.y);
            acc[2] += b2f(u0.z) + b2f(u1.z) + b2f(u2.z) + b2f(u3.z);
            acc[3] += b2f(u0.w) + b2f(u1.w) + b2f(u2.w) + b2f(u3.w);
        } else {
            ushort2 u0 = *reinterpret_cast<const ushort2*>(A + (size_t)s0 * F + f0);
            ushort2 u1 = *reinterpret_cast<const ushort2*>(A + (size_t)s1 * F + f0);
            ushort2 u2 = *reinterpret_cast<const ushort2*>(A + (size_t)s2 * F + f0);
            ushort2 u3 = *reinterpret_cast<const ushort2*>(A + (size_t)s3 * F + f0);
            acc[0] += b2f(u0.x) + b2f(u1.x) + b2f(u2.x) + b2f(u3.x);
            acc[1] += b2f(u0.y) + b2f(u1.y) + b2f(u2.y) + b2f(u3.y);
        }
    }
    for (; e < hi; ++e) {
        const unsigned short* sr = A + (size_t)csr_src[e] * F + f0;
        if (VEC == 4) {
            ushort4 u = *reinterpret_cast<const ushort4*>(sr);
            acc[0] += b2f(u.x); acc[1] += b2f(u.y); acc[2] += b2f(u.z); acc[3] += b2f(u.w);
        } else {
            ushort2 u = *reinterpret_cast<const ushort2*>(sr);
            acc[0] += b2f(u.x); acc[1] += b2f(u.y);
        }
    }

    const float di = dinv_in[node];
#pragma unroll
    for (int v = 0; v < VEC; ++v) {
        float xv = acc[v] * di + bias[f0 + v];
        if (ACTMODE == 1) xv = fmaxf(xv, 0.0f);
        else              xv = 1.0f / (1.0f + expf(-xv)) + 1e-8f;
        acc[v] = xv;
    }
    if (Yb) {
        unsigned short* yr = Yb + (size_t)node * F + f0;
        if (VEC == 4) {
            ushort4 u; u.x = f2b(acc[0]); u.y = f2b(acc[1]); u.z = f2b(acc[2]); u.w = f2b(acc[3]);
            *reinterpret_cast<ushort4*>(yr) = u;
        } else {
            ushort2 u; u.x = f2b(acc[0]); u.y = f2b(acc[1]);
            *reinterpret_cast<ushort2*>(yr) = u;
        }
    }
    if (OUTF32) {
        float* yf = Yf + (size_t)node * F + f0;
        if (VEC == 4) *reinterpret_cast<float4*>(yf) = make_float4(acc[0], acc[1], acc[2], acc[3]);
        else          *reinterpret_cast<float2*>(yf) = make_float2(acc[0], acc[1]);
    }
}

// ---------------- launcher ----------------
extern "C" void kernel_launch(void* const* d_in, const int* in_sizes, int n_in,
                              void* d_out, int out_size, void* d_ws, size_t ws_size,
                              hipStream_t stream)
{
    const float* x   = (const float*)d_in[0];
    const int*   src = (const int*)d_in[1];
    const int*   dst = (const int*)d_in[2];
    const float* Wg1 = (const float*)d_in[3];
    const float* bg1 = (const float*)d_in[4];
    const float* Wg2 = (const float*)d_in[5];
    const float* bg2 = (const float*)d_in[6];
    const float* Wg3 = (const float*)d_in[7];
    const float* bg3 = (const float*)d_in[8];
    const float* W1  = (const float*)d_in[9];
    const float* b1  = (const float*)d_in[10];
    const float* W2  = (const float*)d_in[11];
    const float* b2  = (const float*)d_in[12];
    const float* W3  = (const float*)d_in[13];
    const float* b3  = (const float*)d_in[14];

    float* out  = (float*)d_out;
    float* prob = out;                     // [N x 64]
    float* gnn  = out + (size_t)NN * ACT;  // [N x 128]

    char* p = (char*)d_ws;
    auto alloc = [&](size_t bytes) { char* r = p; p += (bytes + 255) & ~(size_t)255; return r; };
    float*          dinv_out = (float*)alloc((size_t)NN * 4);
    float*          dinv_in  = (float*)alloc((size_t)NN * 4);
    int*            cnt2     = (int*)alloc((size_t)2 * NN * 4);   // [cnt_in | cnt_out]
    int*            row_st   = (int*)alloc((size_t)(NN + 1) * 4);
    int*            cursor   = (int*)alloc((size_t)NN * 4);
    int*            partial  = (int*)alloc((size_t)SCAN_NB * 4);
    int*            csr_src  = (int*)alloc((size_t)EE * 4);
    unsigned short* xb       = (unsigned short*)alloc((size_t)NN * OBS * 2);
    unsigned short* WT1      = (unsigned short*)alloc((size_t)HID * OBS * 2);
    unsigned short* WT2      = (unsigned short*)alloc((size_t)HID * HID * 2);
    unsigned short* WT3      = (unsigned short*)alloc((size_t)EMB * HID * 2);
    unsigned short* WTm1     = (unsigned short*)alloc((size_t)MLPH * EMB * 2);
    unsigned short* WTm2     = (unsigned short*)alloc((size_t)MLPH * MLPH * 2);
    unsigned short* WTm3     = (unsigned short*)alloc((size_t)ACT * MLPH * 2);
    unsigned short* actA     = (unsigned short*)alloc((size_t)NN * 512 * 2);
    unsigned short* actB     = (unsigned short*)alloc((size_t)NN * 512 * 2);

    int* cnt_in  = cnt2;
    int* cnt_out = cnt2 + NN;

    // --- conversions ---
    f32_to_bf16_vec<<<(NN * OBS / 4 + 255) / 256, 256, 0, stream>>>(x, xb, NN * OBS);
    wt_all<<<dim3(256, 6), dim3(32, 8), 0, stream>>>(Wg1, Wg2, Wg3, W1, W2, W3,
                                                     WT1, WT2, WT3, WTm1, WTm2, WTm3);

    // --- degrees + CSR (3-phase parallel scan) ---
    hipMemsetAsync(cnt2, 0, (size_t)2 * NN * 4, stream);
    edge_deg<<<1024, 256, 0, stream>>>(src, dst, cnt_out, cnt_in, EE);
    csr_partials<<<SCAN_NB, 256, 0, stream>>>(cnt_in, cnt_out, partial, dinv_in, dinv_out);
    scan_partials<<<1, 128, 0, stream>>>(partial, row_st);
    csr_scan_write<<<SCAN_NB, 256, 0, stream>>>(cnt_in, partial, row_st, cursor);
    fill_csr<<<1024, 256, 0, stream>>>(src, dst, cursor, csr_src, EE);

    const int rb = (NN + GBM - 1) / GBM;   // 157 row tiles
    const int gb = (NN + 3) / 4;

    // --- GCN layer 1 ---
    gemm_bf16<<<dim3(rb, HID / GBN), 256, 0, stream>>>(xb, WT1, NN, OBS, HID, dinv_out, nullptr, 0, actA, nullptr);
    gather_bf16<HID, 1, false><<<gb, 256, 0, stream>>>(actA, actB, nullptr, row_st, csr_src, dinv_in, bg1);

    // --- GCN layer 2 ---
    gemm_bf16<<<dim3(rb, HID / GBN), 256, 0, stream>>>(actB, WT2, NN, HID, HID, dinv_out, nullptr, 0, actA, nullptr);
    gather_bf16<HID, 1, false><<<gb, 256, 0, stream>>>(actA, actB, nullptr, row_st, csr_src, dinv_in, bg2);

    // --- GCN layer 3 -> gnn (f32, in d_out) + bf16 copy for MLP ---
    gemm_bf16<<<dim3(rb, 1), 256, 0, stream>>>(actB, WT3, NN, HID, EMB, dinv_out, nullptr, 0, actA, nullptr);
    gather_bf16<EMB, 2, true><<<gb, 256, 0, stream>>>(actA, actB, gnn, row_st, csr_src, dinv_in, bg3);

    // --- MLP (softmax fused into last GEMM) ---
    gemm_bf16<<<dim3(rb, MLPH / GBN), 256, 0, stream>>>(actB, WTm1, NN, EMB, MLPH, nullptr, b1, 1, actA, nullptr);
    gemm_bf16<<<dim3(rb, MLPH / GBN), 256, 0, stream>>>(actA, WTm2, NN, MLPH, MLPH, nullptr, b2, 1, actB, nullptr);
    gemm_bf16<<<dim3(rb, 1), 256, 0, stream>>>(actB, WTm3, NN, MLPH, ACT, nullptr, b3, 3, nullptr, prob);
}

// Round 6
// 271.083 us; speedup vs baseline: 4.0813x; 1.0088x over previous
//
#include <hip/hip_runtime.h>
#include <hip/hip_bf16.h>
#include <math.h>

// Problem constants (match reference)
#define NN   20000
#define EE   320000
#define OBS  256
#define HID  256
#define EMB  128
#define MLPH 512
#define ACT  64

#define SCAN_NB ((NN + 255) / 256)   // 79 scan blocks

using short8 = __attribute__((ext_vector_type(8))) short;
using f32x4  = __attribute__((ext_vector_type(4))) float;

__device__ __forceinline__ unsigned short f2b(float v) {
    __hip_bfloat16 b = __float2bfloat16(v);
    return *reinterpret_cast<unsigned short*>(&b);
}
__device__ __forceinline__ float b2f(unsigned short u) {
    return __uint_as_float(((unsigned int)u) << 16);
}

// ---------------- fused prep: x->bf16, 6 weight transposes, zero histograms ----------------
// flat grid ranges: [0,2500) x-convert (8 f32/thread)
//                   [2500,3012) weight transpose tiles (32x32)
//                   [3012,3052) zero cnt2 (2*NN ints)
#define PREP_CONV 2500
#define PREP_WT   (PREP_CONV + 512)
#define PREP_ZERO (PREP_WT + 40)

__global__ __launch_bounds__(256) void prep_all(
    const float* __restrict__ x, unsigned short* __restrict__ xb,
    const float* W0, const float* W1, const float* W2,
    const float* W3, const float* W4, const float* W5,
    unsigned short* T0, unsigned short* T1, unsigned short* T2,
    unsigned short* T3, unsigned short* T4, unsigned short* T5,
    int* __restrict__ cnt2)
{
    __shared__ float t[32][33];
    const int b   = blockIdx.x;
    const int tid = threadIdx.x;

    if (b < PREP_CONV) {
        const int i = (b * 256 + tid) * 8;   // NN*OBS = 5,120,000 = 2500*256*8 exactly
        float4 a = *reinterpret_cast<const float4*>(&x[i]);
        float4 c = *reinterpret_cast<const float4*>(&x[i + 4]);
        short8 o;
        o[0] = (short)f2b(a.x); o[1] = (short)f2b(a.y); o[2] = (short)f2b(a.z); o[3] = (short)f2b(a.w);
        o[4] = (short)f2b(c.x); o[5] = (short)f2b(c.y); o[6] = (short)f2b(c.z); o[7] = (short)f2b(c.w);
        *reinterpret_cast<short8*>(&xb[i]) = o;
        return;
    }
    if (b < PREP_WT) {
        int local = b - PREP_CONV;
        const float* W; unsigned short* T; int K, N;
        if      (local < 64)  { W = W0; T = T0; K = OBS;  N = HID; }
        else if (local < 128) { W = W1; T = T1; K = HID;  N = HID;  local -= 64; }
        else if (local < 160) { W = W2; T = T2; K = HID;  N = EMB;  local -= 128; }
        else if (local < 224) { W = W3; T = T3; K = EMB;  N = MLPH; local -= 160; }
        else if (local < 480) { W = W4; T = T4; K = MLPH; N = MLPH; local -= 224; }
        else                  { W = W5; T = T5; K = MLPH; N = ACT;  local -= 480; }
        const int tk = K / 32;
        const int k0 = (local % tk) * 32;
        const int n0 = (local / tk) * 32;
        const int tx = tid & 31, ty = tid >> 5;   // 32 x 8
        for (int i = 0; i < 32; i += 8)
            t[ty + i][tx] = W[(size_t)(k0 + ty + i) * N + (n0 + tx)];
        __syncthreads();
        for (int i = 0; i < 32; i += 8)
            T[(size_t)(n0 + ty + i) * K + (k0 + tx)] = f2b(t[tx][ty + i]);
        return;
    }
    {
        const int i = ((b - PREP_WT) * 256 + tid) * 4;
        if (i + 3 < 2 * NN) {
            *reinterpret_cast<int4*>(&cnt2[i]) = make_int4(0, 0, 0, 0);
        } else {
            for (int j = i; j < 2 * NN; ++j) cnt2[j] = 0;
        }
    }
}

// ---------------- degree / CSR kernels (int4-vectorized over edges) ----------------
__global__ __launch_bounds__(256) void edge_deg(const int* __restrict__ src, const int* __restrict__ dst,
                                                int* __restrict__ cnt_out, int* __restrict__ cnt_in) {
    const int i4 = blockIdx.x * 256 + threadIdx.x;
    if (i4 * 4 >= EE) return;
    int4 s = *reinterpret_cast<const int4*>(&src[i4 * 4]);
    int4 d = *reinterpret_cast<const int4*>(&dst[i4 * 4]);
    atomicAdd(&cnt_out[s.x], 1); atomicAdd(&cnt_out[s.y], 1);
    atomicAdd(&cnt_out[s.z], 1); atomicAdd(&cnt_out[s.w], 1);
    atomicAdd(&cnt_in[d.x], 1);  atomicAdd(&cnt_in[d.y], 1);
    atomicAdd(&cnt_in[d.z], 1);  atomicAdd(&cnt_in[d.w], 1);
}

// phase 1: per-block partial sums of cnt_in + dinv computation
__global__ __launch_bounds__(256) void csr_partials(
    const int* __restrict__ cnt_in, const int* __restrict__ cnt_out,
    int* __restrict__ partial, float* __restrict__ dinv_in, float* __restrict__ dinv_out)
{
    const int i = blockIdx.x * 256 + threadIdx.x;
    int v = 0;
    if (i < NN) {
        v = cnt_in[i];
        dinv_in[i]  = rsqrtf((float)(v + 1));
        dinv_out[i] = rsqrtf((float)(cnt_out[i] + 1));
    }
    int s = v;
#pragma unroll
    for (int o = 32; o >= 1; o >>= 1) s += __shfl_xor(s, o);
    __shared__ int ws[4];
    const int lane = threadIdx.x & 63, wv = threadIdx.x >> 6;
    if (lane == 0) ws[wv] = s;
    __syncthreads();
    if (threadIdx.x == 0) partial[blockIdx.x] = ws[0] + ws[1] + ws[2] + ws[3];
}

// phase 2 (merged): every block scans the 79 partials in LDS, then does its
// block-local exclusive scan -> row_start, cursor (coalesced)
__global__ __launch_bounds__(256) void csr_scan_write(
    const int* __restrict__ cnt_in, const int* __restrict__ partial,
    int* __restrict__ row_start, int* __restrict__ cursor)
{
    __shared__ int praw[128], pscan[128];
    const int b   = blockIdx.x;
    const int tid = threadIdx.x;
    if (tid < 128) {
        int v = (tid < SCAN_NB) ? partial[tid] : 0;
        praw[tid] = v; pscan[tid] = v;
    }
    __syncthreads();
    for (int off = 1; off < 128; off <<= 1) {
        int u = (tid < 128 && tid >= off) ? pscan[tid - off] : 0;
        __syncthreads();
        if (tid < 128) pscan[tid] += u;
        __syncthreads();
    }
    const int bexcl = pscan[b] - praw[b];

    const int i = b * 256 + tid;
    const int lane = tid & 63, wv = tid >> 6;
    int v = (i < NN) ? cnt_in[i] : 0;
    int x = v;
#pragma unroll
    for (int o = 1; o < 64; o <<= 1) {
        int u = __shfl_up(x, o);
        if (lane >= o) x += u;
    }
    __shared__ int wsum[4];
    if (lane == 63) wsum[wv] = x;
    __syncthreads();
    int wadd = 0;
    for (int w = 0; w < wv; ++w) wadd += wsum[w];
    const int excl = x - v + wadd + bexcl;
    if (i < NN) { row_start[i] = excl; cursor[i] = excl; }
    if (b == 0 && tid == 0) row_start[NN] = EE;
}

__global__ __launch_bounds__(256) void fill_csr(const int* __restrict__ src, const int* __restrict__ dst,
                                                int* __restrict__ cursor, int* __restrict__ csr_src)
{
    const int i4 = blockIdx.x * 256 + threadIdx.x;
    if (i4 * 4 >= EE) return;
    int4 s = *reinterpret_cast<const int4*>(&src[i4 * 4]);
    int4 d = *reinterpret_cast<const int4*>(&dst[i4 * 4]);
    csr_src[atomicAdd(&cursor[d.x], 1)] = s.x;
    csr_src[atomicAdd(&cursor[d.y], 1)] = s.y;
    csr_src[atomicAdd(&cursor[d.z], 1)] = s.z;
    csr_src[atomicAdd(&cursor[d.w], 1)] = s.w;
}

// ---------------- bf16 MFMA GEMM, 2-phase double-buffered global_load_lds ----------------
#define GBM 128
#define GBN 128

__global__ __launch_bounds__(256) void gemm_bf16(
    const unsigned short* __restrict__ X, const unsigned short* __restrict__ WT,
    int M, int K, int N,
    const float* __restrict__ rs, const float* __restrict__ bias, int act,
    unsigned short* __restrict__ Ob, float* __restrict__ Of)
{
    __shared__ __align__(16) unsigned short lds[16384];  // 32 KB: [buf][A/B][128 rows][32]

    const int tid  = threadIdx.x;
    const int lane = tid & 63;
    const int wv   = tid >> 6;
    const int wm   = wv >> 1;
    const int wn   = wv & 1;
    const int row0 = blockIdx.x * GBM;
    const int col0 = blockIdx.y * GBN;

    const int strow  = lane >> 2;                       // 0..15
    const int schunk = (lane & 3) ^ (strow & 3);        // pre-swizzled source chunk

    const int l15 = lane & 15;
    const int kc  = lane >> 4;                          // logical k-chunk 0..3

    f32x4 acc[4][4] = {};

    auto stage = [&](int buf, int k0) {
#pragma unroll
        for (int rr = 0; rr < 2; ++rr) {
            int r  = rr * 64 + wv * 16 + strow;
            int gr = min(row0 + r, M - 1);
            const unsigned short* srcA = X + (size_t)gr * K + k0 + schunk * 8;
            unsigned short* dstA = &lds[buf * 8192 + rr * 2048 + wv * 512];
            __builtin_amdgcn_global_load_lds(
                (const __attribute__((address_space(1))) void*)srcA,
                (__attribute__((address_space(3))) void*)dstA, 16, 0, 0);
        }
#pragma unroll
        for (int rr = 0; rr < 2; ++rr) {
            int r  = rr * 64 + wv * 16 + strow;
            int gn = min(col0 + r, N - 1);
            const unsigned short* srcB = WT + (size_t)gn * K + k0 + schunk * 8;
            unsigned short* dstB = &lds[buf * 8192 + 4096 + rr * 2048 + wv * 512];
            __builtin_amdgcn_global_load_lds(
                (const __attribute__((address_space(1))) void*)srcB,
                (__attribute__((address_space(3))) void*)dstB, 16, 0, 0);
        }
    };

    const int nt = K >> 5;
    int cur = 0;
    stage(0, 0);
    for (int t = 0; t < nt; ++t) {
        if (t + 1 < nt) {
            stage(cur ^ 1, (t + 1) << 5);
            asm volatile("s_waitcnt vmcnt(4)" ::: "memory");
        } else {
            asm volatile("s_waitcnt vmcnt(0)" ::: "memory");
        }
        __builtin_amdgcn_s_barrier();
        __builtin_amdgcn_sched_barrier(0);

        short8 af[4], bfr[4];
#pragma unroll
        for (int mi = 0; mi < 4; ++mi) {
            int fr = wm * 64 + mi * 16 + l15;
            int pc = kc ^ (fr & 3);
            af[mi] = *reinterpret_cast<const short8*>(&lds[cur * 8192 + fr * 32 + pc * 8]);
        }
#pragma unroll
        for (int ni = 0; ni < 4; ++ni) {
            int fn = wn * 64 + ni * 16 + l15;
            int pc = kc ^ (fn & 3);
            bfr[ni] = *reinterpret_cast<const short8*>(&lds[cur * 8192 + 4096 + fn * 32 + pc * 8]);
        }
#pragma unroll
        for (int mi = 0; mi < 4; ++mi)
#pragma unroll
            for (int ni = 0; ni < 4; ++ni)
                acc[mi][ni] = __builtin_amdgcn_mfma_f32_16x16x32_bf16(af[mi], bfr[ni], acc[mi][ni], 0, 0, 0);

        __builtin_amdgcn_s_barrier();
        cur ^= 1;
    }

    if (act == 3) {
        // fused softmax epilogue (N == 64: all cols live in wn==0 fragments)
        if (wn == 1) return;
#pragma unroll
        for (int mi = 0; mi < 4; ++mi) {
#pragma unroll
            for (int q = 0; q < 4; ++q) {
                int r = row0 + wm * 64 + mi * 16 + (lane >> 4) * 4 + q;
                if (r >= M) continue;
                float v[4];
                float mx = -1e30f;
#pragma unroll
                for (int ni = 0; ni < 4; ++ni) {
                    v[ni] = acc[mi][ni][q] + bias[ni * 16 + l15];
                    mx = fmaxf(mx, v[ni]);
                }
#pragma unroll
                for (int o = 8; o >= 1; o >>= 1) mx = fmaxf(mx, __shfl_xor(mx, o));
                float s = 0.0f;
#pragma unroll
                for (int ni = 0; ni < 4; ++ni) { v[ni] = expf(v[ni] - mx); s += v[ni]; }
#pragma unroll
                for (int o = 8; o >= 1; o >>= 1) s += __shfl_xor(s, o);
                float inv = 1.0f / s;
#pragma unroll
                for (int ni = 0; ni < 4; ++ni)
                    Of[(size_t)r * 64 + ni * 16 + l15] = v[ni] * inv;
            }
        }
        return;
    }

#pragma unroll
    for (int mi = 0; mi < 4; ++mi) {
#pragma unroll
        for (int q = 0; q < 4; ++q) {
            int r = row0 + wm * 64 + mi * 16 + (lane >> 4) * 4 + q;
            if (r >= M) continue;
            float rsv = rs ? rs[r] : 1.0f;
#pragma unroll
            for (int ni = 0; ni < 4; ++ni) {
                int c = col0 + wn * 64 + ni * 16 + l15;
                if (c >= N) continue;
                float v = acc[mi][ni][q] * rsv;
                if (bias) v += bias[c];
                if (act == 1) v = fmaxf(v, 0.0f);
                size_t idx = (size_t)r * N + c;
                if (Ob) Ob[idx] = f2b(v);
                if (Of) Of[idx] = v;
            }
        }
    }
}

// ---------------- CSR gather-aggregate + epilogue (bf16 in), 8-deep unrolled ----------------
template <int F, int ACTMODE, bool OUTF32>
__global__ __launch_bounds__(256) void gather_bf16(
    const unsigned short* __restrict__ A, unsigned short* __restrict__ Yb,
    float* __restrict__ Yf,
    const int* __restrict__ row_start, const int* __restrict__ csr_src,
    const float* __restrict__ dinv_in, const float* __restrict__ bias)
{
    constexpr int VEC = F / 64;
    const int wave = threadIdx.x >> 6;
    const int lane = threadIdx.x & 63;
    const int node = blockIdx.x * 4 + wave;
    if (node >= NN) return;
    const int f0 = lane * VEC;

    float acc[VEC];
    {
        const unsigned short* ar = A + (size_t)node * F + f0;
        if (VEC == 4) {
            ushort4 u = *reinterpret_cast<const ushort4*>(ar);
            acc[0] = b2f(u.x); acc[1] = b2f(u.y); acc[2] = b2f(u.z); acc[3] = b2f(u.w);
        } else {
            ushort2 u = *reinterpret_cast<const ushort2*>(ar);
            acc[0] = b2f(u.x); acc[1] = b2f(u.y);
        }
    }
    const int lo = row_start[node];
    const int hi = row_start[node + 1];
    int e = lo;
    const int n8 = lo + ((hi - lo) & ~7);
    for (; e < n8; e += 8) {
        int s[8];
#pragma unroll
        for (int j = 0; j < 8; ++j) s[j] = csr_src[e + j];
        if (VEC == 4) {
            ushort4 u[8];
#pragma unroll
            for (int j = 0; j < 8; ++j)
                u[j] = *reinterpret_cast<const ushort4*>(A + (size_t)s[j] * F + f0);
#pragma unroll
            for (int j = 0; j < 8; ++j) {
                acc[0] += b2f(u[j].x); acc[1] += b2f(u[j].y);
                acc[2] += b2f(u[j].z); acc[3] += b2f(u[j].w);
            }
        } else {
            ushort2 u[8];
#pragma unroll
            for (int j = 0; j < 8; ++j)
                u[j] = *reinterpret_cast<const ushort2*>(A + (size_t)s[j] * F + f0);
#pragma unroll
            for (int j = 0; j < 8; ++j) {
                acc[0] += b2f(u[j].x); acc[1] += b2f(u[j].y);
            }
        }
    }
    for (; e < hi; ++e) {
        const unsigned short* sr = A + (size_t)csr_src[e] * F + f0;
        if (VEC == 4) {
            ushort4 u = *reinterpret_cast<const ushort4*>(sr);
            acc[0] += b2f(u.x); acc[1] += b2f(u.y); acc[2] += b2f(u.z); acc[3] += b2f(u.w);
        } else {
            ushort2 u = *reinterpret_cast<const ushort2*>(sr);
            acc[0] += b2f(u.x); acc[1] += b2f(u.y);
        }
    }

    const float di = dinv_in[node];
#pragma unroll
    for (int v = 0; v < VEC; ++v) {
        float xv = acc[v] * di + bias[f0 + v];
        if (ACTMODE == 1) xv = fmaxf(xv, 0.0f);
        else              xv = 1.0f / (1.0f + expf(-xv)) + 1e-8f;
        acc[v] = xv;
    }
    if (Yb) {
        unsigned short* yr = Yb + (size_t)node * F + f0;
        if (VEC == 4) {
            ushort4 u; u.x = f2b(acc[0]); u.y = f2b(acc[1]); u.z = f2b(acc[2]); u.w = f2b(acc[3]);
            *reinterpret_cast<ushort4*>(yr) = u;
        } else {
            ushort2 u; u.x = f2b(acc[0]); u.y = f2b(acc[1]);
            *reinterpret_cast<ushort2*>(yr) = u;
        }
    }
    if (OUTF32) {
        float* yf = Yf + (size_t)node * F + f0;
        if (VEC == 4) *reinterpret_cast<float4*>(yf) = make_float4(acc[0], acc[1], acc[2], acc[3]);
        else          *reinterpret_cast<float2*>(yf) = make_float2(acc[0], acc[1]);
    }
}

// ---------------- launcher ----------------
extern "C" void kernel_launch(void* const* d_in, const int* in_sizes, int n_in,
                              void* d_out, int out_size, void* d_ws, size_t ws_size,
                              hipStream_t stream)
{
    const float* x   = (const float*)d_in[0];
    const int*   src = (const int*)d_in[1];
    const int*   dst = (const int*)d_in[2];
    const float* Wg1 = (const float*)d_in[3];
    const float* bg1 = (const float*)d_in[4];
    const float* Wg2 = (const float*)d_in[5];
    const float* bg2 = (const float*)d_in[6];
    const float* Wg3 = (const float*)d_in[7];
    const float* bg3 = (const float*)d_in[8];
    const float* W1  = (const float*)d_in[9];
    const float* b1  = (const float*)d_in[10];
    const float* W2  = (const float*)d_in[11];
    const float* b2  = (const float*)d_in[12];
    const float* W3  = (const float*)d_in[13];
    const float* b3  = (const float*)d_in[14];

    float* out  = (float*)d_out;
    float* prob = out;                     // [N x 64]
    float* gnn  = out + (size_t)NN * ACT;  // [N x 128]

    char* p = (char*)d_ws;
    auto alloc = [&](size_t bytes) { char* r = p; p += (bytes + 255) & ~(size_t)255; return r; };
    float*          dinv_out = (float*)alloc((size_t)NN * 4);
    float*          dinv_in  = (float*)alloc((size_t)NN * 4);
    int*            cnt2     = (int*)alloc((size_t)2 * NN * 4);   // [cnt_in | cnt_out]
    int*            row_st   = (int*)alloc((size_t)(NN + 1) * 4);
    int*            cursor   = (int*)alloc((size_t)NN * 4);
    int*            partial  = (int*)alloc((size_t)SCAN_NB * 4);
    int*            csr_src  = (int*)alloc((size_t)EE * 4);
    unsigned short* xb       = (unsigned short*)alloc((size_t)NN * OBS * 2);
    unsigned short* WT1      = (unsigned short*)alloc((size_t)HID * OBS * 2);
    unsigned short* WT2      = (unsigned short*)alloc((size_t)HID * HID * 2);
    unsigned short* WT3      = (unsigned short*)alloc((size_t)EMB * HID * 2);
    unsigned short* WTm1     = (unsigned short*)alloc((size_t)MLPH * EMB * 2);
    unsigned short* WTm2     = (unsigned short*)alloc((size_t)MLPH * MLPH * 2);
    unsigned short* WTm3     = (unsigned short*)alloc((size_t)ACT * MLPH * 2);
    unsigned short* actA     = (unsigned short*)alloc((size_t)NN * 512 * 2);
    unsigned short* actB     = (unsigned short*)alloc((size_t)NN * 512 * 2);

    int* cnt_in  = cnt2;
    int* cnt_out = cnt2 + NN;

    // --- fused prep: conversions + weight transposes + histogram zeroing ---
    prep_all<<<PREP_ZERO, 256, 0, stream>>>(x, xb, Wg1, Wg2, Wg3, W1, W2, W3,
                                            WT1, WT2, WT3, WTm1, WTm2, WTm3, cnt2);

    // --- degrees + CSR (parallel scan, merged phases) ---
    const int eb = (EE / 4 + 255) / 256;   // 313 edge blocks
    edge_deg<<<eb, 256, 0, stream>>>(src, dst, cnt_out, cnt_in);
    csr_partials<<<SCAN_NB, 256, 0, stream>>>(cnt_in, cnt_out, partial, dinv_in, dinv_out);
    csr_scan_write<<<SCAN_NB, 256, 0, stream>>>(cnt_in, partial, row_st, cursor);
    fill_csr<<<eb, 256, 0, stream>>>(src, dst, cursor, csr_src);

    const int rb = (NN + GBM - 1) / GBM;   // 157 row tiles
    const int gb = (NN + 3) / 4;

    // --- GCN layer 1 ---
    gemm_bf16<<<dim3(rb, HID / GBN), 256, 0, stream>>>(xb, WT1, NN, OBS, HID, dinv_out, nullptr, 0, actA, nullptr);
    gather_bf16<HID, 1, false><<<gb, 256, 0, stream>>>(actA, actB, nullptr, row_st, csr_src, dinv_in, bg1);

    // --- GCN layer 2 ---
    gemm_bf16<<<dim3(rb, HID / GBN), 256, 0, stream>>>(actB, WT2, NN, HID, HID, dinv_out, nullptr, 0, actA, nullptr);
    gather_bf16<HID, 1, false><<<gb, 256, 0, stream>>>(actA, actB, nullptr, row_st, csr_src, dinv_in, bg2);

    // --- GCN layer 3 -> gnn (f32, in d_out) + bf16 copy for MLP ---
    gemm_bf16<<<dim3(rb, 1), 256, 0, stream>>>(actB, WT3, NN, HID, EMB, dinv_out, nullptr, 0, actA, nullptr);
    gather_bf16<EMB, 2, true><<<gb, 256, 0, stream>>>(actA, actB, gnn, row_st, csr_src, dinv_in, bg3);

    // --- MLP (softmax fused into last GEMM) ---
    gemm_bf16<<<dim3(rb, MLPH / GBN), 256, 0, stream>>>(actB, WTm1, NN, EMB, MLPH, nullptr, b1, 1, actA, nullptr);
    gemm_bf16<<<dim3(rb, MLPH / GBN), 256, 0, stream>>>(actA, WTm2, NN, MLPH, MLPH, nullptr, b2, 1, actB, nullptr);
    gemm_bf16<<<dim3(rb, 1), 256, 0, stream>>>(actB, WTm3, NN, MLPH, ACT, nullptr, b3, 3, nullptr, prob);
}